// Round 9
// baseline (302.689 us; speedup 1.0000x reference)
//
#include <hip/hip_runtime.h>

#define B_ 8
#define C_ 256
#define H_ 96
#define W_ 128
#define HW_ (H_*W_)
#define PATCH_ 21
#define MAXD_ 20
#define WP_ 176                  // padded B width in granules (pos = w+2dx, 0..175)
#define NG1_ (B_*32*H_*W_)       // 3,145,728 A granules
#define NG2_ (B_*32*H_*WP_)      // 4,325,376 B granules
#define WS_NEED_ (((size_t)NG1_ + (size_t)NG2_) * 16)
#define NTASK_ (B_*H_*PATCH_*2)  // 32256 wave-tasks (2 w-halves)
#define NBLKM_ (NTASK_/4)        // 8064 blocks of 4 waves

typedef __fp16 half2_t __attribute__((ext_vector_type(2)));
typedef _Float16 f16x8 __attribute__((ext_vector_type(8)));
typedef float f32x4 __attribute__((ext_vector_type(4)));
typedef float f4_t __attribute__((ext_vector_type(4)));
typedef __fp16 h8_t __attribute__((ext_vector_type(8)));

// ---------------- prepass: f32 -> packed f16 granules ----------------
__global__ __launch_bounds__(256) void pack_kernel(
    const float* __restrict__ in1, const float* __restrict__ in2,
    f16x8* __restrict__ ws1, f16x8* __restrict__ ws2) {
  const int t = blockIdx.x * 256 + threadIdx.x;
  float f[8];
  if (t < NG1_) {
    const int w  = t & (W_ - 1);
    const int h  = (t >> 7) % H_;
    const int cb = (t / HW_) & 31;
    const int b  = t / (32 * HW_);
    const float* p = in1 + ((size_t)(b * C_ + 8 * cb) * H_ + h) * W_ + w;
#pragma unroll
    for (int j = 0; j < 8; ++j) f[j] = p[(size_t)j * HW_];
    f16x8 pk;
#pragma unroll
    for (int jj = 0; jj < 4; ++jj) {
      half2_t q = __builtin_amdgcn_cvt_pkrtz(f[2 * jj], f[2 * jj + 1]);
      pk[2 * jj]     = (_Float16)q.x;
      pk[2 * jj + 1] = (_Float16)q.y;
    }
    ws1[t] = pk;
  } else {
    const int g  = t - NG1_;
    const int wp = g % WP_;
    int rest = g / WP_;
    const int h  = rest % H_;
    rest /= H_;
    const int cb = rest & 31;
    const int b  = rest >> 5;
    const int w2 = wp - MAXD_;
    const bool v = (unsigned)w2 < (unsigned)W_;
#pragma unroll
    for (int j = 0; j < 8; ++j) f[j] = 0.f;
    if (v) {
      const float* p = in2 + ((size_t)(b * C_ + 8 * cb) * H_ + h) * W_ + w2;
#pragma unroll
      for (int j = 0; j < 8; ++j) f[j] = p[(size_t)j * HW_];
    }
    f16x8 pk;
#pragma unroll
    for (int jj = 0; jj < 4; ++jj) {
      half2_t q = __builtin_amdgcn_cvt_pkrtz(f[2 * jj], f[2 * jj + 1]);
      pk[2 * jj]     = (_Float16)q.x;
      pk[2 * jj + 1] = (_Float16)q.y;
    }
    ws2[g] = pk;
  }
}

// ---------------- main: banded-Gram MFMA with register double-buffer ----------------
__global__ __launch_bounds__(256) void corr_mfma(
    const f16x8* __restrict__ ws1,
    const f16x8* __restrict__ ws2,
    float* __restrict__ out) {
  const int wid  = threadIdx.x >> 6;
  const int lane = threadIdx.x & 63;
  const int n  = lane & 15;    // MFMA col (B free dim)
  const int kg = lane >> 4;    // k-group

  int blk = blockIdx.x;
  blk = (blk & 7) * (NBLKM_ / 8) + (blk >> 3);   // XCD-chunked (8064 = 8*1008)
  int task = blk * 4 + wid;
  const int thalf = task & 1; task >>= 1;
  const int dy = task % PATCH_; task /= PATCH_;
  const int h  = task % H_;
  const int b  = task / H_;
  const int t0 = thalf * 4;
  const int h2 = h + 2 * dy - MAXD_;
  const bool rowok = (unsigned)h2 < (unsigned)H_;

  f32x4 acc[4][4];   // [tt][d]
#pragma unroll
  for (int tt = 0; tt < 4; ++tt)
#pragma unroll
    for (int d = 0; d < 4; ++d) acc[tt][d] = f32x4{0.f, 0.f, 0.f, 0.f};

  if (rowok) {
    const f16x8* pA = ws1 + (((size_t)(b * 32 + kg) * H_ + h) * W_ + t0 * 16 + n);
    const f16x8* pB = ws2 + (((size_t)(b * 32 + kg) * H_ + h2) * WP_ + t0 * 16 + n);
    const size_t sA = (size_t)4 * H_ * W_;    // granule-plane stride per 32-ch chunk
    const size_t sB = (size_t)4 * H_ * WP_;

    f16x8 A0[4], B0[7], A1[4], B1[7];

    auto loadf = [&](f16x8 (&A)[4], f16x8 (&B)[7], int chunk) {
      const f16x8* a = pA + (size_t)chunk * sA;
      const f16x8* bb = pB + (size_t)chunk * sB;
#pragma unroll
      for (int tt = 0; tt < 4; ++tt) A[tt] = a[tt * 16];
#pragma unroll
      for (int u = 0; u < 7; ++u) B[u] = bb[u * 16];
    };
    auto compute = [&](f16x8 (&A)[4], f16x8 (&B)[7]) {
#pragma unroll
      for (int tt = 0; tt < 4; ++tt)
#pragma unroll
        for (int d = 0; d < 4; ++d)
          acc[tt][d] = __builtin_amdgcn_mfma_f32_16x16x32_f16(
              A[tt], B[tt + d], acc[tt][d], 0, 0, 0);
    };

    loadf(A0, B0, 0);
#pragma unroll
    for (int i = 0; i < 4; ++i) {
      loadf(A1, B1, 2 * i + 1);     // prefetch odd chunk
      compute(A0, B0);              // compute even chunk 2i
      if (2 * i + 2 < 8) loadf(A0, B0, 2 * i + 2);   // prefetch next even
      compute(A1, B1);              // compute odd chunk 2i+1
    }
  }

  // epilogue: D entry (tt,d,r): m=kg*4+r, w=16*(t0+tt)+m, 2dx=16d+n-m
  const float sc = 1.0f / (float)C_;
#pragma unroll
  for (int tt = 0; tt < 4; ++tt) {
#pragma unroll
    for (int r = 0; r < 4; ++r) {
      const int m = kg * 4 + r;
      const int w = (t0 + tt) * 16 + m;
#pragma unroll
      for (int d = 0; d < 4; ++d) {
        const int v2 = 16 * d + n - m;         // = 2*dx
        if (!(v2 & 1) && v2 >= 0 && v2 <= 40) {
          const int dx = v2 >> 1;
          float val = acc[tt][d][r] * sc;
          val = (val >= 0.f) ? val : 0.1f * val;
          out[(((size_t)b * (PATCH_ * PATCH_) + (size_t)(dy * PATCH_ + dx)) * H_ + h) * W_ + w] = val;
        }
      }
    }
  }
}

// ---------------- fallback (round-6 verified): f32 inputs, dot2 path ----------------
__device__ __forceinline__ float fdot2f(half2_t a, half2_t b, float c) {
  return __builtin_amdgcn_fdot2(a, b, c, false);
}
__device__ __forceinline__ int swz(int pos) { return pos ^ ((pos >> 3) & 7); }
#define P2_ 168
#define NBLK_ (B_*24*11)

__global__ __launch_bounds__(256, 2) void corr_kernel(
    const float* __restrict__ in1,
    const float* __restrict__ in2,
    float* __restrict__ out) {
  __shared__ h8_t lds[4 * 2 * P2_];
  const int tid  = threadIdx.x;
  const int wid  = tid >> 6;
  const int lane = tid & 63;
  const int l    = lane & 15;
  const int q    = (lane >> 4) & 1;
  const int gdy  = lane >> 5;
  int bid = blockIdx.x;
  bid = (bid & 7) * (NBLK_ / 8) + (bid >> 3);
  const int dyb = bid % 11;
  const int hg  = (bid / 11) % 24;
  const int b   = bid / (11 * 24);
  const int h   = hg * 4 + wid;
  const int dy   = 2 * dyb + gdy;
  const int w0   = 8 * l;
  const int rel0 = 20 * q;
  float acc[8][11];
#pragma unroll
  for (int j = 0; j < 8; ++j)
#pragma unroll
    for (int i = 0; i < 11; ++i) acc[j][i] = 0.f;
  const int wbase   = wid * (2 * P2_);
  const int ldsbase = wbase + gdy * P2_;
  for (int c0 = 0; c0 < C_; c0 += 8) {
#pragma unroll
    for (int s = lane; s < 2 * P2_; s += 64) {
      const int dyidx = (s >= P2_) ? 1 : 0;
      const int pos = s - P2_ * dyidx;
      const int h2 = h + 2 * (2 * dyb + dyidx) - MAXD_;
      const int w2 = pos - MAXD_;
      const bool v = ((unsigned)h2 < (unsigned)H_) && ((unsigned)w2 < (unsigned)W_);
      float f[8];
      if (v) {
        const float* bp = in2 + ((size_t)(b * C_ + c0) * H_ + h2) * W_ + w2;
#pragma unroll
        for (int j = 0; j < 8; ++j) f[j] = bp[(size_t)j * HW_];
      } else {
#pragma unroll
        for (int j = 0; j < 8; ++j) f[j] = 0.f;
      }
      h8_t pk;
#pragma unroll
      for (int jj = 0; jj < 4; ++jj) {
        half2_t p2 = __builtin_amdgcn_cvt_pkrtz(f[2 * jj], f[2 * jj + 1]);
        pk[2 * jj]     = p2.x;
        pk[2 * jj + 1] = p2.y;
      }
      lds[wbase + dyidx * P2_ + swz(pos)] = pk;
    }
    const float* a_base = in1 + ((size_t)(b * C_ + c0) * H_ + h) * W_ + w0;
    half2_t a2[8][4];
#pragma unroll
    for (int jj = 0; jj < 4; ++jj) {
      f4_t lo0 = *(const f4_t*)(a_base + (size_t)(2 * jj) * HW_);
      f4_t lo1 = *(const f4_t*)(a_base + (size_t)(2 * jj) * HW_ + 4);
      f4_t hi0 = *(const f4_t*)(a_base + (size_t)(2 * jj + 1) * HW_);
      f4_t hi1 = *(const f4_t*)(a_base + (size_t)(2 * jj + 1) * HW_ + 4);
#pragma unroll
      for (int j = 0; j < 4; ++j) {
        a2[j][jj]     = __builtin_amdgcn_cvt_pkrtz(lo0[j], hi0[j]);
        a2[j + 4][jj] = __builtin_amdgcn_cvt_pkrtz(lo1[j], hi1[j]);
      }
    }
    h8_t wv[8];
#pragma unroll
    for (int k = 0; k < 8; ++k)
      wv[k] = lds[ldsbase + swz(w0 + rel0 + k)];
#pragma unroll
    for (int i = 0; i < 11; ++i) {
#pragma unroll
      for (int j = 0; j < 8; ++j) {
        const h8_t wj = wv[(2 * i + j) & 7];
#pragma unroll
        for (int jj = 0; jj < 4; ++jj) {
          half2_t bb;
          bb.x = wj[2 * jj];
          bb.y = wj[2 * jj + 1];
          acc[j][i] = fdot2f(a2[j][jj], bb, acc[j][i]);
        }
      }
      if (i < 10) {
        wv[(2 * i + 8) & 7] = lds[ldsbase + swz(w0 + rel0 + 2 * i + 8)];
        wv[(2 * i + 9) & 7] = lds[ldsbase + swz(w0 + rel0 + 2 * i + 9)];
      }
    }
  }
  if (dy < PATCH_) {
    const float s = 1.f / (float)C_;
#pragma unroll
    for (int i = 0; i < 11; ++i) {
      if (q && i == 0) continue;
      const int dx = 10 * q + i;
      float* ob = out + ((size_t)(b * (PATCH_ * PATCH_) + dy * PATCH_ + dx) * H_ + h) * W_ + w0;
      f4_t v0, v1;
#pragma unroll
      for (int j = 0; j < 4; ++j) {
        float x = acc[j][i] * s;
        v0[j] = (x >= 0.f) ? x : 0.1f * x;
        float y = acc[j + 4][i] * s;
        v1[j] = (y >= 0.f) ? y : 0.1f * y;
      }
      *(f4_t*)ob = v0;
      *(f4_t*)(ob + 4) = v1;
    }
  }
}

extern "C" void kernel_launch(void* const* d_in, const int* in_sizes, int n_in,
                              void* d_out, int out_size, void* d_ws, size_t ws_size,
                              hipStream_t stream) {
  (void)in_sizes; (void)n_in; (void)out_size;
  const float* in1 = (const float*)d_in[0];
  const float* in2 = (const float*)d_in[1];
  float* out = (float*)d_out;

  if (ws_size >= WS_NEED_) {
    f16x8* ws1 = (f16x8*)d_ws;
    f16x8* ws2 = ws1 + NG1_;
    pack_kernel<<<dim3((NG1_ + NG2_) / 256), dim3(256), 0, stream>>>(in1, in2, ws1, ws2);
    corr_mfma<<<dim3(NBLKM_), dim3(256), 0, stream>>>(ws1, ws2, out);
  } else {
    corr_kernel<<<dim3(NBLK_), dim3(256), 0, stream>>>(in1, in2, out);
  }
}

// Round 10
// 286.707 us; speedup vs baseline: 1.0557x; 1.0557x over previous
//
#include <hip/hip_runtime.h>

#define B_ 8
#define C_ 256
#define H_ 96
#define W_ 128
#define HW_ (H_*W_)
#define PATCH_ 21
#define MAXD_ 20
#define WP_ 176                  // padded B width in granules (pos = w+2dx, 0..175)
#define NG1_ (B_*32*H_*W_)       // 3,145,728 A granules
#define NG2_ (B_*32*H_*WP_)      // 4,325,376 B granules
#define WS_NEED_ (((size_t)NG1_ + (size_t)NG2_) * 16)
#define NTASK_ (B_*H_*PATCH_*2)  // 32256 wave-tasks (2 w-halves)
#define NBLKM_ (NTASK_/4)        // 8064 blocks of 4 waves

typedef __fp16 half2_t __attribute__((ext_vector_type(2)));
typedef _Float16 f16x8 __attribute__((ext_vector_type(8)));
typedef float f32x4 __attribute__((ext_vector_type(4)));
typedef float f4_t __attribute__((ext_vector_type(4)));
typedef __fp16 h8_t __attribute__((ext_vector_type(8)));

// ---------------- prepass: f32 -> packed f16 granules ----------------
__global__ __launch_bounds__(256) void pack_kernel(
    const float* __restrict__ in1, const float* __restrict__ in2,
    f16x8* __restrict__ ws1, f16x8* __restrict__ ws2) {
  const int t = blockIdx.x * 256 + threadIdx.x;
  float f[8];
  if (t < NG1_) {
    const int w  = t & (W_ - 1);
    const int h  = (t >> 7) % H_;
    const int cb = (t / HW_) & 31;
    const int b  = t / (32 * HW_);
    const float* p = in1 + ((size_t)(b * C_ + 8 * cb) * H_ + h) * W_ + w;
#pragma unroll
    for (int j = 0; j < 8; ++j) f[j] = p[(size_t)j * HW_];
    f16x8 pk;
#pragma unroll
    for (int jj = 0; jj < 4; ++jj) {
      half2_t q = __builtin_amdgcn_cvt_pkrtz(f[2 * jj], f[2 * jj + 1]);
      pk[2 * jj]     = (_Float16)q.x;
      pk[2 * jj + 1] = (_Float16)q.y;
    }
    ws1[t] = pk;
  } else {
    const int g  = t - NG1_;
    const int wp = g % WP_;
    int rest = g / WP_;
    const int h  = rest % H_;
    rest /= H_;
    const int cb = rest & 31;
    const int b  = rest >> 5;
    const int w2 = wp - MAXD_;
    const bool v = (unsigned)w2 < (unsigned)W_;
#pragma unroll
    for (int j = 0; j < 8; ++j) f[j] = 0.f;
    if (v) {
      const float* p = in2 + ((size_t)(b * C_ + 8 * cb) * H_ + h) * W_ + w2;
#pragma unroll
      for (int j = 0; j < 8; ++j) f[j] = p[(size_t)j * HW_];
    }
    f16x8 pk;
#pragma unroll
    for (int jj = 0; jj < 4; ++jj) {
      half2_t q = __builtin_amdgcn_cvt_pkrtz(f[2 * jj], f[2 * jj + 1]);
      pk[2 * jj]     = (_Float16)q.x;
      pk[2 * jj + 1] = (_Float16)q.y;
    }
    ws2[g] = pk;
  }
}

// ---------------- main: banded-Gram MFMA, batch-issued loads ----------------
__global__ __launch_bounds__(256) void corr_mfma(
    const f16x8* __restrict__ ws1,
    const f16x8* __restrict__ ws2,
    float* __restrict__ out) {
  const int wid  = threadIdx.x >> 6;
  const int lane = threadIdx.x & 63;
  const int n  = lane & 15;    // MFMA col (B free dim)
  const int kg = lane >> 4;    // k-group

  int blk = blockIdx.x;
  blk = (blk & 7) * (NBLKM_ / 8) + (blk >> 3);   // XCD-chunked (8064 = 8*1008)
  int task = blk * 4 + wid;
  const int thalf = task & 1; task >>= 1;
  const int dy = task % PATCH_; task /= PATCH_;
  const int h  = task % H_;
  const int b  = task / H_;
  const int t0 = thalf * 4;
  const int h2 = h + 2 * dy - MAXD_;
  const bool rowok = (unsigned)h2 < (unsigned)H_;

  f32x4 acc[4][4];   // [tt][d]
#pragma unroll
  for (int tt = 0; tt < 4; ++tt)
#pragma unroll
    for (int d = 0; d < 4; ++d) acc[tt][d] = f32x4{0.f, 0.f, 0.f, 0.f};

  if (rowok) {
    const f16x8* pA = ws1 + (((size_t)(b * 32 + kg) * H_ + h) * W_ + t0 * 16 + n);
    const f16x8* pB = ws2 + (((size_t)(b * 32 + kg) * H_ + h2) * WP_ + t0 * 16 + n);
    const size_t sA = (size_t)4 * H_ * W_;    // granule-plane stride per 32-ch chunk
    const size_t sB = (size_t)4 * H_ * WP_;

#pragma unroll
    for (int cb4 = 0; cb4 < 8; ++cb4) {
      const f16x8* a  = pA + (size_t)cb4 * sA;
      const f16x8* bb = pB + (size_t)cb4 * sB;
      f16x8 Af[4], Bf[7];
      // batch-issue all 11 loads of this chunk
#pragma unroll
      for (int tt = 0; tt < 4; ++tt) Af[tt] = a[tt * 16];
#pragma unroll
      for (int u = 0; u < 7; ++u) Bf[u] = bb[u * 16];
      // fence: loads may not sink past here; next chunk's loads may
      // interleave with this chunk's MFMAs (region between barriers)
      __builtin_amdgcn_sched_barrier(0);
#pragma unroll
      for (int tt = 0; tt < 4; ++tt)
#pragma unroll
        for (int d = 0; d < 4; ++d)
          acc[tt][d] = __builtin_amdgcn_mfma_f32_16x16x32_f16(
              Af[tt], Bf[tt + d], acc[tt][d], 0, 0, 0);
    }
  }

  // epilogue: D entry (tt,d,r): m=kg*4+r, w=16*(t0+tt)+m, 2dx=16d+n-m
  const float sc = 1.0f / (float)C_;
#pragma unroll
  for (int tt = 0; tt < 4; ++tt) {
#pragma unroll
    for (int r = 0; r < 4; ++r) {
      const int m = kg * 4 + r;
      const int w = (t0 + tt) * 16 + m;
#pragma unroll
      for (int d = 0; d < 4; ++d) {
        const int v2 = 16 * d + n - m;         // = 2*dx
        if (!(v2 & 1) && v2 >= 0 && v2 <= 40) {
          const int dx = v2 >> 1;
          float val = acc[tt][d][r] * sc;
          val = (val >= 0.f) ? val : 0.1f * val;
          out[(((size_t)b * (PATCH_ * PATCH_) + (size_t)(dy * PATCH_ + dx)) * H_ + h) * W_ + w] = val;
        }
      }
    }
  }
}

// ---------------- fallback (round-6 verified): f32 inputs, dot2 path ----------------
__device__ __forceinline__ float fdot2f(half2_t a, half2_t b, float c) {
  return __builtin_amdgcn_fdot2(a, b, c, false);
}
__device__ __forceinline__ int swz(int pos) { return pos ^ ((pos >> 3) & 7); }
#define P2_ 168
#define NBLK_ (B_*24*11)

__global__ __launch_bounds__(256, 2) void corr_kernel(
    const float* __restrict__ in1,
    const float* __restrict__ in2,
    float* __restrict__ out) {
  __shared__ h8_t lds[4 * 2 * P2_];
  const int tid  = threadIdx.x;
  const int wid  = tid >> 6;
  const int lane = tid & 63;
  const int l    = lane & 15;
  const int q    = (lane >> 4) & 1;
  const int gdy  = lane >> 5;
  int bid = blockIdx.x;
  bid = (bid & 7) * (NBLK_ / 8) + (bid >> 3);
  const int dyb = bid % 11;
  const int hg  = (bid / 11) % 24;
  const int b   = bid / (11 * 24);
  const int h   = hg * 4 + wid;
  const int dy   = 2 * dyb + gdy;
  const int w0   = 8 * l;
  const int rel0 = 20 * q;
  float acc[8][11];
#pragma unroll
  for (int j = 0; j < 8; ++j)
#pragma unroll
    for (int i = 0; i < 11; ++i) acc[j][i] = 0.f;
  const int wbase   = wid * (2 * P2_);
  const int ldsbase = wbase + gdy * P2_;
  for (int c0 = 0; c0 < C_; c0 += 8) {
#pragma unroll
    for (int s = lane; s < 2 * P2_; s += 64) {
      const int dyidx = (s >= P2_) ? 1 : 0;
      const int pos = s - P2_ * dyidx;
      const int h2 = h + 2 * (2 * dyb + dyidx) - MAXD_;
      const int w2 = pos - MAXD_;
      const bool v = ((unsigned)h2 < (unsigned)H_) && ((unsigned)w2 < (unsigned)W_);
      float f[8];
      if (v) {
        const float* bp = in2 + ((size_t)(b * C_ + c0) * H_ + h2) * W_ + w2;
#pragma unroll
        for (int j = 0; j < 8; ++j) f[j] = bp[(size_t)j * HW_];
      } else {
#pragma unroll
        for (int j = 0; j < 8; ++j) f[j] = 0.f;
      }
      h8_t pk;
#pragma unroll
      for (int jj = 0; jj < 4; ++jj) {
        half2_t p2 = __builtin_amdgcn_cvt_pkrtz(f[2 * jj], f[2 * jj + 1]);
        pk[2 * jj]     = p2.x;
        pk[2 * jj + 1] = p2.y;
      }
      lds[wbase + dyidx * P2_ + swz(pos)] = pk;
    }
    const float* a_base = in1 + ((size_t)(b * C_ + c0) * H_ + h) * W_ + w0;
    half2_t a2[8][4];
#pragma unroll
    for (int jj = 0; jj < 4; ++jj) {
      f4_t lo0 = *(const f4_t*)(a_base + (size_t)(2 * jj) * HW_);
      f4_t lo1 = *(const f4_t*)(a_base + (size_t)(2 * jj) * HW_ + 4);
      f4_t hi0 = *(const f4_t*)(a_base + (size_t)(2 * jj + 1) * HW_);
      f4_t hi1 = *(const f4_t*)(a_base + (size_t)(2 * jj + 1) * HW_ + 4);
#pragma unroll
      for (int j = 0; j < 4; ++j) {
        a2[j][jj]     = __builtin_amdgcn_cvt_pkrtz(lo0[j], hi0[j]);
        a2[j + 4][jj] = __builtin_amdgcn_cvt_pkrtz(lo1[j], hi1[j]);
      }
    }
    h8_t wv[8];
#pragma unroll
    for (int k = 0; k < 8; ++k)
      wv[k] = lds[ldsbase + swz(w0 + rel0 + k)];
#pragma unroll
    for (int i = 0; i < 11; ++i) {
#pragma unroll
      for (int j = 0; j < 8; ++j) {
        const h8_t wj = wv[(2 * i + j) & 7];
#pragma unroll
        for (int jj = 0; jj < 4; ++jj) {
          half2_t bb;
          bb.x = wj[2 * jj];
          bb.y = wj[2 * jj + 1];
          acc[j][i] = fdot2f(a2[j][jj], bb, acc[j][i]);
        }
      }
      if (i < 10) {
        wv[(2 * i + 8) & 7] = lds[ldsbase + swz(w0 + rel0 + 2 * i + 8)];
        wv[(2 * i + 9) & 7] = lds[ldsbase + swz(w0 + rel0 + 2 * i + 9)];
      }
    }
  }
  if (dy < PATCH_) {
    const float s = 1.f / (float)C_;
#pragma unroll
    for (int i = 0; i < 11; ++i) {
      if (q && i == 0) continue;
      const int dx = 10 * q + i;
      float* ob = out + ((size_t)(b * (PATCH_ * PATCH_) + dy * PATCH_ + dx) * H_ + h) * W_ + w0;
      f4_t v0, v1;
#pragma unroll
      for (int j = 0; j < 4; ++j) {
        float x = acc[j][i] * s;
        v0[j] = (x >= 0.f) ? x : 0.1f * x;
        float y = acc[j + 4][i] * s;
        v1[j] = (y >= 0.f) ? y : 0.1f * y;
      }
      *(f4_t*)ob = v0;
      *(f4_t*)(ob + 4) = v1;
    }
  }
}

extern "C" void kernel_launch(void* const* d_in, const int* in_sizes, int n_in,
                              void* d_out, int out_size, void* d_ws, size_t ws_size,
                              hipStream_t stream) {
  (void)in_sizes; (void)n_in; (void)out_size;
  const float* in1 = (const float*)d_in[0];
  const float* in2 = (const float*)d_in[1];
  float* out = (float*)d_out;

  if (ws_size >= WS_NEED_) {
    f16x8* ws1 = (f16x8*)d_ws;
    f16x8* ws2 = ws1 + NG1_;
    pack_kernel<<<dim3((NG1_ + NG2_) / 256), dim3(256), 0, stream>>>(in1, in2, ws1, ws2);
    corr_mfma<<<dim3(NBLKM_), dim3(256), 0, stream>>>(ws1, ws2, out);
  } else {
    corr_kernel<<<dim3(NBLK_), dim3(256), 0, stream>>>(in1, in2, out);
  }
}

// Round 11
// 228.461 us; speedup vs baseline: 1.3249x; 1.2550x over previous
//
#include <hip/hip_runtime.h>

#define B_ 8
#define C_ 256
#define H_ 96
#define W_ 128
#define HW_ (H_*W_)
#define PATCH_ 21
#define MAXD_ 20
#define WP_ 176
#define NG1_ (B_*8*H_*W_*4)      // 3,145,728 A granules ([b][cg][h][w][p])
#define NG2_ (B_*8*H_*WP_*4)     // 4,325,376 B granules ([b][cg][h][wp][p])
#define WS_NEED_ (((size_t)NG1_ + (size_t)NG2_) * 16)
#define NTASK_ (B_*H_*PATCH_*2)  // 32256 wave-tasks
#define NBLKM_ (NTASK_/4)        // 8064 blocks of 4 waves

typedef __fp16 half2_t __attribute__((ext_vector_type(2)));
typedef _Float16 f16x8 __attribute__((ext_vector_type(8)));
typedef float f32x4 __attribute__((ext_vector_type(4)));
typedef float f4_t __attribute__((ext_vector_type(4)));
typedef __fp16 h8_t __attribute__((ext_vector_type(8)));

// ---------------- prepass: f32 -> packed f16 granules, plane-interleaved ----------------
// granule = 8 ch (cg*32 + p*8 + j) at one (h, w). layout: [b][cg][h][w][p]
__global__ __launch_bounds__(256) void pack_kernel(
    const float* __restrict__ in1, const float* __restrict__ in2,
    f16x8* __restrict__ ws1, f16x8* __restrict__ ws2) {
  const int t = blockIdx.x * 256 + threadIdx.x;
  float f[8];
  if (t < NG1_) {
    const int p  = t & 3;
    const int w  = (t >> 2) & (W_ - 1);
    const int h  = (t >> 9) % H_;
    const int cg = (t / (4 * W_ * H_)) & 7;
    const int b  = t / (4 * W_ * H_ * 8);
    const float* sp = in1 + ((size_t)(b * C_ + cg * 32 + p * 8) * H_ + h) * W_ + w;
#pragma unroll
    for (int j = 0; j < 8; ++j) f[j] = sp[(size_t)j * HW_];
    f16x8 pk;
#pragma unroll
    for (int jj = 0; jj < 4; ++jj) {
      half2_t q = __builtin_amdgcn_cvt_pkrtz(f[2 * jj], f[2 * jj + 1]);
      pk[2 * jj]     = (_Float16)q.x;
      pk[2 * jj + 1] = (_Float16)q.y;
    }
    ws1[t] = pk;
  } else {
    const int g  = t - NG1_;
    const int p  = g & 3;
    const int wp = (g >> 2) % WP_;
    int rest = g / (4 * WP_);
    const int h  = rest % H_;
    rest /= H_;
    const int cg = rest & 7;
    const int b  = rest >> 3;
    const int w2 = wp - MAXD_;
    const bool v = (unsigned)w2 < (unsigned)W_;
#pragma unroll
    for (int j = 0; j < 8; ++j) f[j] = 0.f;
    if (v) {
      const float* sp = in2 + ((size_t)(b * C_ + cg * 32 + p * 8) * H_ + h) * W_ + w2;
#pragma unroll
      for (int j = 0; j < 8; ++j) f[j] = sp[(size_t)j * HW_];
    }
    f16x8 pk;
#pragma unroll
    for (int jj = 0; jj < 4; ++jj) {
      half2_t q = __builtin_amdgcn_cvt_pkrtz(f[2 * jj], f[2 * jj + 1]);
      pk[2 * jj]     = (_Float16)q.x;
      pk[2 * jj + 1] = (_Float16)q.y;
    }
    ws2[g] = pk;
  }
}

// ---------------- main: banded-Gram MFMA, contiguous bursts + LDS-coalesced stores ----------------
__global__ __launch_bounds__(256) void corr_mfma(
    const f16x8* __restrict__ ws1,
    const f16x8* __restrict__ ws2,
    float* __restrict__ out) {
  __shared__ float slds[4][PATCH_][65];   // per-wave transpose buffer (65: bank spread)

  const int wid  = threadIdx.x >> 6;
  const int lane = threadIdx.x & 63;
  const int n  = lane & 15;    // MFMA col / m-row lane dim
  const int kg = lane >> 4;    // k-group -> plane

  int blk = blockIdx.x;
  blk = (blk & 7) * (NBLKM_ / 8) + (blk >> 3);   // XCD-chunked
  int task = blk * 4 + wid;
  const int thalf = task & 1; task >>= 1;
  const int dy = task % PATCH_; task /= PATCH_;
  const int h  = task % H_;
  const int b  = task / H_;
  const int t0 = thalf * 4;
  const int h2 = h + 2 * dy - MAXD_;
  const bool rowok = (unsigned)h2 < (unsigned)H_;

  f32x4 acc[4][4];   // [tt][d]
#pragma unroll
  for (int tt = 0; tt < 4; ++tt)
#pragma unroll
    for (int d = 0; d < 4; ++d) acc[tt][d] = f32x4{0.f, 0.f, 0.f, 0.f};

  if (rowok) {
    // plane-interleaved: lane term (n*4 + kg); wave's 64 lanes = 64 consecutive granules
    const f16x8* pA = ws1 + ((((size_t)b * 8 * H_ + h) * W_) + t0 * 16 + n) * 4 + kg;
    const f16x8* pB = ws2 + ((((size_t)b * 8 * H_ + h2) * WP_) + t0 * 16 + n) * 4 + kg;
    const size_t sA = (size_t)H_ * W_ * 4;    // granules per 32-ch group
    const size_t sB = (size_t)H_ * WP_ * 4;

#pragma unroll
    for (int cg = 0; cg < 8; ++cg) {
      const f16x8* a  = pA + (size_t)cg * sA;
      const f16x8* bb = pB + (size_t)cg * sB;
      f16x8 Af[4], Bf[7];
#pragma unroll
      for (int tt = 0; tt < 4; ++tt) Af[tt] = a[tt * 64];
#pragma unroll
      for (int u = 0; u < 7; ++u) Bf[u] = bb[u * 64];
      __builtin_amdgcn_sched_barrier(0);
#pragma unroll
      for (int tt = 0; tt < 4; ++tt)
#pragma unroll
        for (int d = 0; d < 4; ++d)
          acc[tt][d] = __builtin_amdgcn_mfma_f32_16x16x32_f16(
              Af[tt], Bf[tt + d], acc[tt][d], 0, 0, 0);
    }
  }

  // ---- scatter D into per-wave LDS: slds[dx][wloc], wloc = 16tt + m, m = kg*4+r ----
#pragma unroll
  for (int tt = 0; tt < 4; ++tt) {
#pragma unroll
    for (int r = 0; r < 4; ++r) {
      const int m = kg * 4 + r;
#pragma unroll
      for (int d = 0; d < 4; ++d) {
        const int v2 = 16 * d + n - m;         // = 2*dx
        if (!(v2 & 1) && v2 >= 0 && v2 <= 40)
          slds[wid][v2 >> 1][tt * 16 + m] = acc[tt][d][r];
      }
    }
  }
  // (per-wave LDS region + in-wave DS ordering: no barrier needed)

  // ---- coalesced stores: 21 × 256B contiguous ----
  const float sc = 1.0f / (float)C_;
#pragma unroll
  for (int dx = 0; dx < PATCH_; ++dx) {
    float v = slds[wid][dx][lane] * sc;
    v = (v >= 0.f) ? v : 0.1f * v;
    out[(((size_t)b * (PATCH_ * PATCH_) + (size_t)(dy * PATCH_ + dx)) * H_ + h) * W_ + t0 * 16 + lane] = v;
  }
}

// ---------------- fallback (round-6 verified): f32 inputs, dot2 path ----------------
__device__ __forceinline__ float fdot2f(half2_t a, half2_t b, float c) {
  return __builtin_amdgcn_fdot2(a, b, c, false);
}
__device__ __forceinline__ int swz(int pos) { return pos ^ ((pos >> 3) & 7); }
#define P2_ 168
#define NBLK_ (B_*24*11)

__global__ __launch_bounds__(256, 2) void corr_kernel(
    const float* __restrict__ in1,
    const float* __restrict__ in2,
    float* __restrict__ out) {
  __shared__ h8_t lds[4 * 2 * P2_];
  const int tid  = threadIdx.x;
  const int wid  = tid >> 6;
  const int lane = tid & 63;
  const int l    = lane & 15;
  const int q    = (lane >> 4) & 1;
  const int gdy  = lane >> 5;
  int bid = blockIdx.x;
  bid = (bid & 7) * (NBLK_ / 8) + (bid >> 3);
  const int dyb = bid % 11;
  const int hg  = (bid / 11) % 24;
  const int b   = bid / (11 * 24);
  const int h   = hg * 4 + wid;
  const int dy   = 2 * dyb + gdy;
  const int w0   = 8 * l;
  const int rel0 = 20 * q;
  float acc[8][11];
#pragma unroll
  for (int j = 0; j < 8; ++j)
#pragma unroll
    for (int i = 0; i < 11; ++i) acc[j][i] = 0.f;
  const int wbase   = wid * (2 * P2_);
  const int ldsbase = wbase + gdy * P2_;
  for (int c0 = 0; c0 < C_; c0 += 8) {
#pragma unroll
    for (int s = lane; s < 2 * P2_; s += 64) {
      const int dyidx = (s >= P2_) ? 1 : 0;
      const int pos = s - P2_ * dyidx;
      const int h2 = h + 2 * (2 * dyb + dyidx) - MAXD_;
      const int w2 = pos - MAXD_;
      const bool v = ((unsigned)h2 < (unsigned)H_) && ((unsigned)w2 < (unsigned)W_);
      float f[8];
      if (v) {
        const float* bp = in2 + ((size_t)(b * C_ + c0) * H_ + h2) * W_ + w2;
#pragma unroll
        for (int j = 0; j < 8; ++j) f[j] = bp[(size_t)j * HW_];
      } else {
#pragma unroll
        for (int j = 0; j < 8; ++j) f[j] = 0.f;
      }
      h8_t pk;
#pragma unroll
      for (int jj = 0; jj < 4; ++jj) {
        half2_t p2 = __builtin_amdgcn_cvt_pkrtz(f[2 * jj], f[2 * jj + 1]);
        pk[2 * jj]     = p2.x;
        pk[2 * jj + 1] = p2.y;
      }
      lds[wbase + dyidx * P2_ + swz(pos)] = pk;
    }
    const float* a_base = in1 + ((size_t)(b * C_ + c0) * H_ + h) * W_ + w0;
    half2_t a2[8][4];
#pragma unroll
    for (int jj = 0; jj < 4; ++jj) {
      f4_t lo0 = *(const f4_t*)(a_base + (size_t)(2 * jj) * HW_);
      f4_t lo1 = *(const f4_t*)(a_base + (size_t)(2 * jj) * HW_ + 4);
      f4_t hi0 = *(const f4_t*)(a_base + (size_t)(2 * jj + 1) * HW_);
      f4_t hi1 = *(const f4_t*)(a_base + (size_t)(2 * jj + 1) * HW_ + 4);
#pragma unroll
      for (int j = 0; j < 4; ++j) {
        a2[j][jj]     = __builtin_amdgcn_cvt_pkrtz(lo0[j], hi0[j]);
        a2[j + 4][jj] = __builtin_amdgcn_cvt_pkrtz(lo1[j], hi1[j]);
      }
    }
    h8_t wv[8];
#pragma unroll
    for (int k = 0; k < 8; ++k)
      wv[k] = lds[ldsbase + swz(w0 + rel0 + k)];
#pragma unroll
    for (int i = 0; i < 11; ++i) {
#pragma unroll
      for (int j = 0; j < 8; ++j) {
        const h8_t wj = wv[(2 * i + j) & 7];
#pragma unroll
        for (int jj = 0; jj < 4; ++jj) {
          half2_t bb;
          bb.x = wj[2 * jj];
          bb.y = wj[2 * jj + 1];
          acc[j][i] = fdot2f(a2[j][jj], bb, acc[j][i]);
        }
      }
      if (i < 10) {
        wv[(2 * i + 8) & 7] = lds[ldsbase + swz(w0 + rel0 + 2 * i + 8)];
        wv[(2 * i + 9) & 7] = lds[ldsbase + swz(w0 + rel0 + 2 * i + 9)];
      }
    }
  }
  if (dy < PATCH_) {
    const float s = 1.f / (float)C_;
#pragma unroll
    for (int i = 0; i < 11; ++i) {
      if (q && i == 0) continue;
      const int dx = 10 * q + i;
      float* ob = out + ((size_t)(b * (PATCH_ * PATCH_) + dy * PATCH_ + dx) * H_ + h) * W_ + w0;
      f4_t v0, v1;
#pragma unroll
      for (int j = 0; j < 4; ++j) {
        float x = acc[j][i] * s;
        v0[j] = (x >= 0.f) ? x : 0.1f * x;
        float y = acc[j + 4][i] * s;
        v1[j] = (y >= 0.f) ? y : 0.1f * y;
      }
      *(f4_t*)ob = v0;
      *(f4_t*)(ob + 4) = v1;
    }
  }
}

extern "C" void kernel_launch(void* const* d_in, const int* in_sizes, int n_in,
                              void* d_out, int out_size, void* d_ws, size_t ws_size,
                              hipStream_t stream) {
  (void)in_sizes; (void)n_in; (void)out_size;
  const float* in1 = (const float*)d_in[0];
  const float* in2 = (const float*)d_in[1];
  float* out = (float*)d_out;

  if (ws_size >= WS_NEED_) {
    f16x8* ws1 = (f16x8*)d_ws;
    f16x8* ws2 = ws1 + NG1_;
    pack_kernel<<<dim3((NG1_ + NG2_) / 256), dim3(256), 0, stream>>>(in1, in2, ws1, ws2);
    corr_mfma<<<dim3(NBLKM_), dim3(256), 0, stream>>>(ws1, ws2, out);
  } else {
    corr_kernel<<<dim3(NBLK_), dim3(256), 0, stream>>>(in1, in2, out);
  }
}

// Round 12
// 198.885 us; speedup vs baseline: 1.5219x; 1.1487x over previous
//
#include <hip/hip_runtime.h>

#define B_ 8
#define C_ 256
#define H_ 96
#define W_ 128
#define HW_ (H_*W_)
#define PATCH_ 21
#define MAXD_ 20
#define WP_ 176
#define NG1_ (B_*8*H_*W_*4)      // A granules [b][cg][h][w][p]
#define NG2_ (B_*8*H_*WP_*4)     // B granules [b][cg][h][wp][p]
#define WS_NEED_ (((size_t)NG1_ + (size_t)NG2_) * 16)
#define NBLK2_ (B_*H_*6)         // 4608 blocks: (b, h2, dyo*2+thalf)

typedef __fp16 half2_t __attribute__((ext_vector_type(2)));
typedef _Float16 f16x8 __attribute__((ext_vector_type(8)));
typedef float f32x4 __attribute__((ext_vector_type(4)));
typedef float f4_t __attribute__((ext_vector_type(4)));
typedef __fp16 h8_t __attribute__((ext_vector_type(8)));

__device__ __forceinline__ void gload_lds16(const f16x8* gsrc, f16x8* ldst) {
  __builtin_amdgcn_global_load_lds(
      (const __attribute__((address_space(1))) void*)gsrc,
      (__attribute__((address_space(3))) void*)ldst, 16, 0, 0);
}

// ---------------- prepass: f32 -> packed f16 granules, plane-interleaved ----------------
__global__ __launch_bounds__(256) void pack_kernel(
    const float* __restrict__ in1, const float* __restrict__ in2,
    f16x8* __restrict__ ws1, f16x8* __restrict__ ws2) {
  const int t = blockIdx.x * 256 + threadIdx.x;
  float f[8];
  if (t < NG1_) {
    const int p  = t & 3;
    const int w  = (t >> 2) & (W_ - 1);
    const int h  = (t >> 9) % H_;
    const int cg = (t / (4 * W_ * H_)) & 7;
    const int b  = t / (4 * W_ * H_ * 8);
    const float* sp = in1 + ((size_t)(b * C_ + cg * 32 + p * 8) * H_ + h) * W_ + w;
#pragma unroll
    for (int j = 0; j < 8; ++j) f[j] = sp[(size_t)j * HW_];
    f16x8 pk;
#pragma unroll
    for (int jj = 0; jj < 4; ++jj) {
      half2_t q = __builtin_amdgcn_cvt_pkrtz(f[2 * jj], f[2 * jj + 1]);
      pk[2 * jj]     = (_Float16)q.x;
      pk[2 * jj + 1] = (_Float16)q.y;
    }
    ws1[t] = pk;
  } else {
    const int g  = t - NG1_;
    const int p  = g & 3;
    const int wp = (g >> 2) % WP_;
    int rest = g / (4 * WP_);
    const int h  = rest % H_;
    rest /= H_;
    const int cg = rest & 7;
    const int b  = rest >> 3;
    const int w2 = wp - MAXD_;
    const bool v = (unsigned)w2 < (unsigned)W_;
#pragma unroll
    for (int j = 0; j < 8; ++j) f[j] = 0.f;
    if (v) {
      const float* sp = in2 + ((size_t)(b * C_ + cg * 32 + p * 8) * H_ + h) * W_ + w2;
#pragma unroll
      for (int j = 0; j < 8; ++j) f[j] = sp[(size_t)j * HW_];
    }
    f16x8 pk;
#pragma unroll
    for (int jj = 0; jj < 4; ++jj) {
      half2_t q = __builtin_amdgcn_cvt_pkrtz(f[2 * jj], f[2 * jj + 1]);
      pk[2 * jj]     = (_Float16)q.x;
      pk[2 * jj + 1] = (_Float16)q.y;
    }
    ws2[g] = pk;
  }
}

// ---------------- zero-fill outputs whose h2 = h+2dy-20 is out of range ----------------
__global__ __launch_bounds__(128) void zfill_kernel(float* __restrict__ out) {
  const int t = threadIdx.x;          // w
  int blk = blockIdx.x;               // b*210 + dy*10 + slot
  const int slot = blk % 10; blk /= 10;
  const int dy = blk % 21; const int b = blk / 21;
  const int cnt = (dy < 10) ? (20 - 2 * dy) : ((dy > 10) ? (2 * dy - 20) : 0);
  const int hbase = (dy < 10) ? 0 : (116 - 2 * dy);
#pragma unroll
  for (int k = slot * 2; k < slot * 2 + 2; ++k) {
    if (k >= cnt) break;
    const int h = hbase + k;
    for (int dx = 0; dx < PATCH_; ++dx)
      out[(((size_t)b * 441 + dy * 21 + dx) * H_ + h) * W_ + t] = 0.f;
  }
}

// ---------------- main: B-row shared in LDS across 8 dy-waves ----------------
__global__ __launch_bounds__(512, 2) void corr_mfma2(
    const f16x8* __restrict__ ws1,
    const f16x8* __restrict__ ws2,
    float* __restrict__ out) {
  // union: staging [2][448] f16x8 = 14336 B  |  transpose 8*1365 floats = 43680 B
  __shared__ __align__(16) float lds_f[8 * 1365];
  f16x8* ldsB = (f16x8*)lds_f;

  const int wid  = threadIdx.x >> 6;
  const int lane = threadIdx.x & 63;
  const int n  = lane & 15;
  const int kg = lane >> 4;
  const int src_perm = n * 4 + kg;    // pre-swizzle: LDS slot i holds granule perm(i)

  int blk = blockIdx.x;
  blk = (blk & 7) * (NBLK2_ / 8) + (blk >> 3);   // XCD-chunked; 576 blocks = one b
  const int ht = blk % 6;
  const int h2 = (blk / 6) % H_;
  const int b  = blk / (6 * H_);
  const int thalf = ht & 1;
  const int dyo   = ht >> 1;
  const int dy = dyo * 8 + wid;
  const int h  = h2 + 20 - 2 * dy;
  const bool valid = (dy <= MAXD_) && ((unsigned)h < (unsigned)H_);
  const int t0 = thalf * 4;

  // B segment (row h2, w-tiles t0..t0+6): granule base
  const f16x8* ws2base = ws2 + ((((size_t)(b * 8) * H_ + h2) * WP_ + t0 * 16) * 4);
  const size_t sBseg = (size_t)H_ * WP_ * 4;    // per cg
  const f16x8* pA = valid
      ? (ws1 + ((((size_t)(b * 8) * H_ + h) * W_ + t0 * 16) * 4 + src_perm))
      : ws1;
  const size_t sA = (size_t)H_ * W_ * 4;

  f32x4 acc[4][4];
#pragma unroll
  for (int tt = 0; tt < 4; ++tt)
#pragma unroll
    for (int d = 0; d < 4; ++d) acc[tt][d] = f32x4{0.f, 0.f, 0.f, 0.f};

  // prologue: stage chunk 0 into buf 0
  if (wid < 7) gload_lds16(ws2base + wid * 64 + src_perm, ldsB + wid * 64);

#pragma unroll
  for (int cg = 0; cg < 8; ++cg) {
    __syncthreads();   // drains stage(cg); syncs buffer reuse
    if (cg < 7 && wid < 7)
      gload_lds16(ws2base + (size_t)(cg + 1) * sBseg + wid * 64 + src_perm,
                  ldsB + ((cg + 1) & 1) * 448 + wid * 64);
    if (valid) {
      const f16x8* a = pA + (size_t)cg * sA;
      f16x8 Af[4], Bf[7];
#pragma unroll
      for (int tt = 0; tt < 4; ++tt) Af[tt] = a[tt * 64];
      const int bufo = (cg & 1) * 448;
#pragma unroll
      for (int u = 0; u < 7; ++u) Bf[u] = ldsB[bufo + u * 64 + lane];
#pragma unroll
      for (int tt = 0; tt < 4; ++tt)
#pragma unroll
        for (int d = 0; d < 4; ++d)
          acc[tt][d] = __builtin_amdgcn_mfma_f32_16x16x32_f16(
              Af[tt], Bf[tt + d], acc[tt][d], 0, 0, 0);
    }
  }

  __syncthreads();   // staging dead; reuse LDS for transpose
  float* slds = lds_f + wid * (PATCH_ * 65);
  if (valid) {
#pragma unroll
    for (int tt = 0; tt < 4; ++tt) {
#pragma unroll
      for (int r = 0; r < 4; ++r) {
        const int m = kg * 4 + r;
#pragma unroll
        for (int d = 0; d < 4; ++d) {
          const int v2 = 16 * d + n - m;     // = 2*dx
          if (!(v2 & 1) && v2 >= 0 && v2 <= 40)
            slds[(v2 >> 1) * 65 + tt * 16 + m] = acc[tt][d][r];
        }
      }
    }
    const float sc = 1.0f / (float)C_;
#pragma unroll
    for (int dx = 0; dx < PATCH_; ++dx) {
      float v = slds[dx * 65 + lane] * sc;
      v = (v >= 0.f) ? v : 0.1f * v;
      out[(((size_t)b * 441 + dy * 21 + dx) * H_ + h) * W_ + thalf * 64 + lane] = v;
    }
  }
}

// ---------------- fallback (round-6 verified): f32 inputs, dot2 path ----------------
__device__ __forceinline__ float fdot2f(half2_t a, half2_t b, float c) {
  return __builtin_amdgcn_fdot2(a, b, c, false);
}
__device__ __forceinline__ int swz(int pos) { return pos ^ ((pos >> 3) & 7); }
#define P2_ 168
#define NBLK_ (B_*24*11)

__global__ __launch_bounds__(256, 2) void corr_kernel(
    const float* __restrict__ in1,
    const float* __restrict__ in2,
    float* __restrict__ out) {
  __shared__ h8_t lds[4 * 2 * P2_];
  const int tid  = threadIdx.x;
  const int wid  = tid >> 6;
  const int lane = tid & 63;
  const int l    = lane & 15;
  const int q    = (lane >> 4) & 1;
  const int gdy  = lane >> 5;
  int bid = blockIdx.x;
  bid = (bid & 7) * (NBLK_ / 8) + (bid >> 3);
  const int dyb = bid % 11;
  const int hg  = (bid / 11) % 24;
  const int b   = bid / (11 * 24);
  const int h   = hg * 4 + wid;
  const int dy   = 2 * dyb + gdy;
  const int w0   = 8 * l;
  const int rel0 = 20 * q;
  float acc[8][11];
#pragma unroll
  for (int j = 0; j < 8; ++j)
#pragma unroll
    for (int i = 0; i < 11; ++i) acc[j][i] = 0.f;
  const int wbase   = wid * (2 * P2_);
  const int ldsbase = wbase + gdy * P2_;
  for (int c0 = 0; c0 < C_; c0 += 8) {
#pragma unroll
    for (int s = lane; s < 2 * P2_; s += 64) {
      const int dyidx = (s >= P2_) ? 1 : 0;
      const int pos = s - P2_ * dyidx;
      const int h2 = h + 2 * (2 * dyb + dyidx) - MAXD_;
      const int w2 = pos - MAXD_;
      const bool v = ((unsigned)h2 < (unsigned)H_) && ((unsigned)w2 < (unsigned)W_);
      float f[8];
      if (v) {
        const float* bp = in2 + ((size_t)(b * C_ + c0) * H_ + h2) * W_ + w2;
#pragma unroll
        for (int j = 0; j < 8; ++j) f[j] = bp[(size_t)j * HW_];
      } else {
#pragma unroll
        for (int j = 0; j < 8; ++j) f[j] = 0.f;
      }
      h8_t pk;
#pragma unroll
      for (int jj = 0; jj < 4; ++jj) {
        half2_t p2 = __builtin_amdgcn_cvt_pkrtz(f[2 * jj], f[2 * jj + 1]);
        pk[2 * jj]     = p2.x;
        pk[2 * jj + 1] = p2.y;
      }
      lds[wbase + dyidx * P2_ + swz(pos)] = pk;
    }
    const float* a_base = in1 + ((size_t)(b * C_ + c0) * H_ + h) * W_ + w0;
    half2_t a2[8][4];
#pragma unroll
    for (int jj = 0; jj < 4; ++jj) {
      f4_t lo0 = *(const f4_t*)(a_base + (size_t)(2 * jj) * HW_);
      f4_t lo1 = *(const f4_t*)(a_base + (size_t)(2 * jj) * HW_ + 4);
      f4_t hi0 = *(const f4_t*)(a_base + (size_t)(2 * jj + 1) * HW_);
      f4_t hi1 = *(const f4_t*)(a_base + (size_t)(2 * jj + 1) * HW_ + 4);
#pragma unroll
      for (int j = 0; j < 4; ++j) {
        a2[j][jj]     = __builtin_amdgcn_cvt_pkrtz(lo0[j], hi0[j]);
        a2[j + 4][jj] = __builtin_amdgcn_cvt_pkrtz(lo1[j], hi1[j]);
      }
    }
    h8_t wv[8];
#pragma unroll
    for (int k = 0; k < 8; ++k)
      wv[k] = lds[ldsbase + swz(w0 + rel0 + k)];
#pragma unroll
    for (int i = 0; i < 11; ++i) {
#pragma unroll
      for (int j = 0; j < 8; ++j) {
        const h8_t wj = wv[(2 * i + j) & 7];
#pragma unroll
        for (int jj = 0; jj < 4; ++jj) {
          half2_t bb;
          bb.x = wj[2 * jj];
          bb.y = wj[2 * jj + 1];
          acc[j][i] = fdot2f(a2[j][jj], bb, acc[j][i]);
        }
      }
      if (i < 10) {
        wv[(2 * i + 8) & 7] = lds[ldsbase + swz(w0 + rel0 + 2 * i + 8)];
        wv[(2 * i + 9) & 7] = lds[ldsbase + swz(w0 + rel0 + 2 * i + 9)];
      }
    }
  }
  if (dy < PATCH_) {
    const float s = 1.f / (float)C_;
#pragma unroll
    for (int i = 0; i < 11; ++i) {
      if (q && i == 0) continue;
      const int dx = 10 * q + i;
      float* ob = out + ((size_t)(b * (PATCH_ * PATCH_) + dy * PATCH_ + dx) * H_ + h) * W_ + w0;
      f4_t v0, v1;
#pragma unroll
      for (int j = 0; j < 4; ++j) {
        float x = acc[j][i] * s;
        v0[j] = (x >= 0.f) ? x : 0.1f * x;
        float y = acc[j + 4][i] * s;
        v1[j] = (y >= 0.f) ? y : 0.1f * y;
      }
      *(f4_t*)ob = v0;
      *(f4_t*)(ob + 4) = v1;
    }
  }
}

extern "C" void kernel_launch(void* const* d_in, const int* in_sizes, int n_in,
                              void* d_out, int out_size, void* d_ws, size_t ws_size,
                              hipStream_t stream) {
  (void)in_sizes; (void)n_in; (void)out_size;
  const float* in1 = (const float*)d_in[0];
  const float* in2 = (const float*)d_in[1];
  float* out = (float*)d_out;

  if (ws_size >= WS_NEED_) {
    f16x8* ws1 = (f16x8*)d_ws;
    f16x8* ws2 = ws1 + NG1_;
    pack_kernel<<<dim3((NG1_ + NG2_) / 256), dim3(256), 0, stream>>>(in1, in2, ws1, ws2);
    zfill_kernel<<<dim3(B_ * PATCH_ * 10), dim3(128), 0, stream>>>(out);
    corr_mfma2<<<dim3(NBLK2_), dim3(512), 0, stream>>>(ws1, ws2, out);
  } else {
    corr_kernel<<<dim3(NBLK_), dim3(256), 0, stream>>>(in1, in2, out);
  }
}

// Round 13
// 196.218 us; speedup vs baseline: 1.5426x; 1.0136x over previous
//
#include <hip/hip_runtime.h>

#define B_ 8
#define C_ 256
#define H_ 96
#define W_ 128
#define HW_ (H_*W_)
#define PATCH_ 21
#define MAXD_ 20
#define WP_ 176
#define NG1_ (B_*8*H_*W_*4)      // A granules [b][cg][h][w][p]
#define NG2_ (B_*8*H_*WP_*4)     // B granules [b][cg][h][wp][p]
#define WS_NEED_ (((size_t)NG1_ + (size_t)NG2_) * 16)
#define NBLK2_ (B_*H_*6)         // 4608 blocks: (b, h2, dyo*2+thalf)

typedef __fp16 half2_t __attribute__((ext_vector_type(2)));
typedef _Float16 f16x8 __attribute__((ext_vector_type(8)));
typedef float f32x4 __attribute__((ext_vector_type(4)));
typedef float f4_t __attribute__((ext_vector_type(4)));
typedef __fp16 h8_t __attribute__((ext_vector_type(8)));

__device__ __forceinline__ void gload_lds16(const f16x8* gsrc, f16x8* ldst) {
  __builtin_amdgcn_global_load_lds(
      (const __attribute__((address_space(1))) void*)gsrc,
      (__attribute__((address_space(3))) void*)ldst, 16, 0, 0);
}

// ---------------- prepass: f32 -> packed f16 granules, plane-interleaved ----------------
__global__ __launch_bounds__(256) void pack_kernel(
    const float* __restrict__ in1, const float* __restrict__ in2,
    f16x8* __restrict__ ws1, f16x8* __restrict__ ws2) {
  const int t = blockIdx.x * 256 + threadIdx.x;
  float f[8];
  if (t < NG1_) {
    const int p  = t & 3;
    const int w  = (t >> 2) & (W_ - 1);
    const int h  = (t >> 9) % H_;
    const int cg = (t / (4 * W_ * H_)) & 7;
    const int b  = t / (4 * W_ * H_ * 8);
    const float* sp = in1 + ((size_t)(b * C_ + cg * 32 + p * 8) * H_ + h) * W_ + w;
#pragma unroll
    for (int j = 0; j < 8; ++j) f[j] = sp[(size_t)j * HW_];
    f16x8 pk;
#pragma unroll
    for (int jj = 0; jj < 4; ++jj) {
      half2_t q = __builtin_amdgcn_cvt_pkrtz(f[2 * jj], f[2 * jj + 1]);
      pk[2 * jj]     = (_Float16)q.x;
      pk[2 * jj + 1] = (_Float16)q.y;
    }
    ws1[t] = pk;
  } else {
    const int g  = t - NG1_;
    const int p  = g & 3;
    const int wp = (g >> 2) % WP_;
    int rest = g / (4 * WP_);
    const int h  = rest % H_;
    rest /= H_;
    const int cg = rest & 7;
    const int b  = rest >> 3;
    const int w2 = wp - MAXD_;
    const bool v = (unsigned)w2 < (unsigned)W_;
#pragma unroll
    for (int j = 0; j < 8; ++j) f[j] = 0.f;
    if (v) {
      const float* sp = in2 + ((size_t)(b * C_ + cg * 32 + p * 8) * H_ + h) * W_ + w2;
#pragma unroll
      for (int j = 0; j < 8; ++j) f[j] = sp[(size_t)j * HW_];
    }
    f16x8 pk;
#pragma unroll
    for (int jj = 0; jj < 4; ++jj) {
      half2_t q = __builtin_amdgcn_cvt_pkrtz(f[2 * jj], f[2 * jj + 1]);
      pk[2 * jj]     = (_Float16)q.x;
      pk[2 * jj + 1] = (_Float16)q.y;
    }
    ws2[g] = pk;
  }
}

// ---------------- zero-fill outputs whose h2 = h+2dy-20 is out of range ----------------
__global__ __launch_bounds__(128) void zfill_kernel(float* __restrict__ out) {
  const int t = threadIdx.x;          // w
  int blk = blockIdx.x;               // b*210 + dy*10 + slot
  const int slot = blk % 10; blk /= 10;
  const int dy = blk % 21; const int b = blk / 21;
  const int cnt = (dy < 10) ? (20 - 2 * dy) : ((dy > 10) ? (2 * dy - 20) : 0);
  const int hbase = (dy < 10) ? 0 : (116 - 2 * dy);
#pragma unroll
  for (int k = slot * 2; k < slot * 2 + 2; ++k) {
    if (k >= cnt) break;
    const int h = hbase + k;
    for (int dx = 0; dx < PATCH_; ++dx)
      out[(((size_t)b * 441 + dy * 21 + dx) * H_ + h) * W_ + t] = 0.f;
  }
}

// ---------------- main: B-row shared in LDS, A register-pipelined ----------------
__global__ __launch_bounds__(512, 2) void corr_mfma2(
    const f16x8* __restrict__ ws1,
    const f16x8* __restrict__ ws2,
    float* __restrict__ out) {
  // union: staging [2][448] f16x8 = 14336 B  |  transpose 8*1365 floats = 43680 B
  __shared__ __align__(16) float lds_f[8 * 1365];
  f16x8* ldsB = (f16x8*)lds_f;

  const int wid  = threadIdx.x >> 6;
  const int lane = threadIdx.x & 63;
  const int n  = lane & 15;
  const int kg = lane >> 4;
  const int src_perm = n * 4 + kg;    // pre-swizzle: LDS slot i holds granule perm(i)

  int blk = blockIdx.x;
  blk = (blk & 7) * (NBLK2_ / 8) + (blk >> 3);   // XCD-chunked; 576 blocks = one b
  const int ht = blk % 6;
  const int h2 = (blk / 6) % H_;
  const int b  = blk / (6 * H_);
  const int thalf = ht & 1;
  const int dyo   = ht >> 1;
  const int dy = dyo * 8 + wid;
  const int h  = h2 + 20 - 2 * dy;
  const bool valid = (dy <= MAXD_) && ((unsigned)h < (unsigned)H_);
  const int t0 = thalf * 4;

  const f16x8* ws2base = ws2 + ((((size_t)(b * 8) * H_ + h2) * WP_ + t0 * 16) * 4);
  const size_t sBseg = (size_t)H_ * WP_ * 4;    // per cg
  const f16x8* pA = valid
      ? (ws1 + ((((size_t)(b * 8) * H_ + h) * W_ + t0 * 16) * 4 + src_perm))
      : ws1;
  const size_t sA = (size_t)H_ * W_ * 4;

  f32x4 acc[4][4];
#pragma unroll
  for (int tt = 0; tt < 4; ++tt)
#pragma unroll
    for (int d = 0; d < 4; ++d) acc[tt][d] = f32x4{0.f, 0.f, 0.f, 0.f};

  // prologue: stage B(0); prefetch A(0) into registers
  if (wid < 7) gload_lds16(ws2base + wid * 64 + src_perm, ldsB + wid * 64);
  f16x8 Acur[4], Anext[4];
#pragma unroll
  for (int tt = 0; tt < 4; ++tt) Acur[tt] = pA[tt * 64];

#pragma unroll
  for (int cg = 0; cg < 8; ++cg) {
    __syncthreads();   // stage(cg) visible; vmcnt drain completes A(cg) too
    if (cg < 7) {
      if (wid < 7)
        gload_lds16(ws2base + (size_t)(cg + 1) * sBseg + wid * 64 + src_perm,
                    ldsB + ((cg + 1) & 1) * 448 + wid * 64);
      // batch-issue A(cg+1); consumed next iteration (covered by chunk cg compute)
#pragma unroll
      for (int tt = 0; tt < 4; ++tt) Anext[tt] = pA[(size_t)(cg + 1) * sA + tt * 64];
    }
    __builtin_amdgcn_sched_barrier(0);   // pin the issues above this compute region
    if (valid) {
      f16x8 Bf[7];
      const int bufo = (cg & 1) * 448;
#pragma unroll
      for (int u = 0; u < 7; ++u) Bf[u] = ldsB[bufo + u * 64 + lane];
#pragma unroll
      for (int tt = 0; tt < 4; ++tt)
#pragma unroll
        for (int d = 0; d < 4; ++d)
          acc[tt][d] = __builtin_amdgcn_mfma_f32_16x16x32_f16(
              Acur[tt], Bf[tt + d], acc[tt][d], 0, 0, 0);
    }
#pragma unroll
    for (int tt = 0; tt < 4; ++tt) Acur[tt] = Anext[tt];   // rename-copy
  }

  __syncthreads();   // staging dead; reuse LDS for transpose
  float* slds = lds_f + wid * (PATCH_ * 65);
  if (valid) {
#pragma unroll
    for (int tt = 0; tt < 4; ++tt) {
#pragma unroll
      for (int r = 0; r < 4; ++r) {
        const int m = kg * 4 + r;
#pragma unroll
        for (int d = 0; d < 4; ++d) {
          const int v2 = 16 * d + n - m;     // = 2*dx
          if (!(v2 & 1) && v2 >= 0 && v2 <= 40)
            slds[(v2 >> 1) * 65 + tt * 16 + m] = acc[tt][d][r];
        }
      }
    }
    const float sc = 1.0f / (float)C_;
#pragma unroll
    for (int dx = 0; dx < PATCH_; ++dx) {
      float v = slds[dx * 65 + lane] * sc;
      v = (v >= 0.f) ? v : 0.1f * v;
      out[(((size_t)b * 441 + dy * 21 + dx) * H_ + h) * W_ + thalf * 64 + lane] = v;
    }
  }
}

// ---------------- fallback (round-6 verified): f32 inputs, dot2 path ----------------
__device__ __forceinline__ float fdot2f(half2_t a, half2_t b, float c) {
  return __builtin_amdgcn_fdot2(a, b, c, false);
}
__device__ __forceinline__ int swz(int pos) { return pos ^ ((pos >> 3) & 7); }
#define P2_ 168
#define NBLK_ (B_*24*11)

__global__ __launch_bounds__(256, 2) void corr_kernel(
    const float* __restrict__ in1,
    const float* __restrict__ in2,
    float* __restrict__ out) {
  __shared__ h8_t lds[4 * 2 * P2_];
  const int tid  = threadIdx.x;
  const int wid  = tid >> 6;
  const int lane = tid & 63;
  const int l    = lane & 15;
  const int q    = (lane >> 4) & 1;
  const int gdy  = lane >> 5;
  int bid = blockIdx.x;
  bid = (bid & 7) * (NBLK_ / 8) + (bid >> 3);
  const int dyb = bid % 11;
  const int hg  = (bid / 11) % 24;
  const int b   = bid / (11 * 24);
  const int h   = hg * 4 + wid;
  const int dy   = 2 * dyb + gdy;
  const int w0   = 8 * l;
  const int rel0 = 20 * q;
  float acc[8][11];
#pragma unroll
  for (int j = 0; j < 8; ++j)
#pragma unroll
    for (int i = 0; i < 11; ++i) acc[j][i] = 0.f;
  const int wbase   = wid * (2 * P2_);
  const int ldsbase = wbase + gdy * P2_;
  for (int c0 = 0; c0 < C_; c0 += 8) {
#pragma unroll
    for (int s = lane; s < 2 * P2_; s += 64) {
      const int dyidx = (s >= P2_) ? 1 : 0;
      const int pos = s - P2_ * dyidx;
      const int h2 = h + 2 * (2 * dyb + dyidx) - MAXD_;
      const int w2 = pos - MAXD_;
      const bool v = ((unsigned)h2 < (unsigned)H_) && ((unsigned)w2 < (unsigned)W_);
      float f[8];
      if (v) {
        const float* bp = in2 + ((size_t)(b * C_ + c0) * H_ + h2) * W_ + w2;
#pragma unroll
        for (int j = 0; j < 8; ++j) f[j] = bp[(size_t)j * HW_];
      } else {
#pragma unroll
        for (int j = 0; j < 8; ++j) f[j] = 0.f;
      }
      h8_t pk;
#pragma unroll
      for (int jj = 0; jj < 4; ++jj) {
        half2_t p2 = __builtin_amdgcn_cvt_pkrtz(f[2 * jj], f[2 * jj + 1]);
        pk[2 * jj]     = p2.x;
        pk[2 * jj + 1] = p2.y;
      }
      lds[wbase + dyidx * P2_ + swz(pos)] = pk;
    }
    const float* a_base = in1 + ((size_t)(b * C_ + c0) * H_ + h) * W_ + w0;
    half2_t a2[8][4];
#pragma unroll
    for (int jj = 0; jj < 4; ++jj) {
      f4_t lo0 = *(const f4_t*)(a_base + (size_t)(2 * jj) * HW_);
      f4_t lo1 = *(const f4_t*)(a_base + (size_t)(2 * jj) * HW_ + 4);
      f4_t hi0 = *(const f4_t*)(a_base + (size_t)(2 * jj + 1) * HW_);
      f4_t hi1 = *(const f4_t*)(a_base + (size_t)(2 * jj + 1) * HW_ + 4);
#pragma unroll
      for (int j = 0; j < 4; ++j) {
        a2[j][jj]     = __builtin_amdgcn_cvt_pkrtz(lo0[j], hi0[j]);
        a2[j + 4][jj] = __builtin_amdgcn_cvt_pkrtz(lo1[j], hi1[j]);
      }
    }
    h8_t wv[8];
#pragma unroll
    for (int k = 0; k < 8; ++k)
      wv[k] = lds[ldsbase + swz(w0 + rel0 + k)];
#pragma unroll
    for (int i = 0; i < 11; ++i) {
#pragma unroll
      for (int j = 0; j < 8; ++j) {
        const h8_t wj = wv[(2 * i + j) & 7];
#pragma unroll
        for (int jj = 0; jj < 4; ++jj) {
          half2_t bb;
          bb.x = wj[2 * jj];
          bb.y = wj[2 * jj + 1];
          acc[j][i] = fdot2f(a2[j][jj], bb, acc[j][i]);
        }
      }
      if (i < 10) {
        wv[(2 * i + 8) & 7] = lds[ldsbase + swz(w0 + rel0 + 2 * i + 8)];
        wv[(2 * i + 9) & 7] = lds[ldsbase + swz(w0 + rel0 + 2 * i + 9)];
      }
    }
  }
  if (dy < PATCH_) {
    const float s = 1.f / (float)C_;
#pragma unroll
    for (int i = 0; i < 11; ++i) {
      if (q && i == 0) continue;
      const int dx = 10 * q + i;
      float* ob = out + ((size_t)(b * (PATCH_ * PATCH_) + dy * PATCH_ + dx) * H_ + h) * W_ + w0;
      f4_t v0, v1;
#pragma unroll
      for (int j = 0; j < 4; ++j) {
        float x = acc[j][i] * s;
        v0[j] = (x >= 0.f) ? x : 0.1f * x;
        float y = acc[j + 4][i] * s;
        v1[j] = (y >= 0.f) ? y : 0.1f * y;
      }
      *(f4_t*)ob = v0;
      *(f4_t*)(ob + 4) = v1;
    }
  }
}

extern "C" void kernel_launch(void* const* d_in, const int* in_sizes, int n_in,
                              void* d_out, int out_size, void* d_ws, size_t ws_size,
                              hipStream_t stream) {
  (void)in_sizes; (void)n_in; (void)out_size;
  const float* in1 = (const float*)d_in[0];
  const float* in2 = (const float*)d_in[1];
  float* out = (float*)d_out;

  if (ws_size >= WS_NEED_) {
    f16x8* ws1 = (f16x8*)d_ws;
    f16x8* ws2 = ws1 + NG1_;
    pack_kernel<<<dim3((NG1_ + NG2_) / 256), dim3(256), 0, stream>>>(in1, in2, ws1, ws2);
    zfill_kernel<<<dim3(B_ * PATCH_ * 10), dim3(128), 0, stream>>>(out);
    corr_mfma2<<<dim3(NBLK2_), dim3(512), 0, stream>>>(ws1, ws2, out);
  } else {
    corr_kernel<<<dim3(NBLK_), dim3(256), 0, stream>>>(in1, in2, out);
  }
}

// Round 14
// 188.129 us; speedup vs baseline: 1.6089x; 1.0430x over previous
//
#include <hip/hip_runtime.h>

#define B_ 8
#define C_ 256
#define H_ 96
#define W_ 128
#define HW_ (H_*W_)
#define PATCH_ 21
#define MAXD_ 20
#define WP_ 176
#define NG1_ (B_*8*H_*W_*4)      // A granules [b][cg][h][w][p]
#define NG2_ (B_*8*H_*WP_*4)     // B granules [b][cg][h][wp][p]
#define WS_NEED_ (((size_t)NG1_ + (size_t)NG2_) * 16)
#define NBLK2_ (B_*H_*6)         // 4608 blocks: (b, h2, dyo*2+thalf)

typedef __fp16 half2_t __attribute__((ext_vector_type(2)));
typedef _Float16 f16x8 __attribute__((ext_vector_type(8)));
typedef float f32x4 __attribute__((ext_vector_type(4)));
typedef float f4_t __attribute__((ext_vector_type(4)));
typedef __fp16 h8_t __attribute__((ext_vector_type(8)));

__device__ __forceinline__ void gload_lds16(const f16x8* gsrc, f16x8* ldst) {
  __builtin_amdgcn_global_load_lds(
      (const __attribute__((address_space(1))) void*)gsrc,
      (__attribute__((address_space(3))) void*)ldst, 16, 0, 0);
}

// ---------------- prepass: f32 -> packed f16 granules, plane-interleaved ----------------
__global__ __launch_bounds__(256) void pack_kernel(
    const float* __restrict__ in1, const float* __restrict__ in2,
    f16x8* __restrict__ ws1, f16x8* __restrict__ ws2) {
  const int t = blockIdx.x * 256 + threadIdx.x;
  float f[8];
  if (t < NG1_) {
    const int p  = t & 3;
    const int w  = (t >> 2) & (W_ - 1);
    const int h  = (t >> 9) % H_;
    const int cg = (t / (4 * W_ * H_)) & 7;
    const int b  = t / (4 * W_ * H_ * 8);
    const float* sp = in1 + ((size_t)(b * C_ + cg * 32 + p * 8) * H_ + h) * W_ + w;
#pragma unroll
    for (int j = 0; j < 8; ++j) f[j] = sp[(size_t)j * HW_];
    f16x8 pk;
#pragma unroll
    for (int jj = 0; jj < 4; ++jj) {
      half2_t q = __builtin_amdgcn_cvt_pkrtz(f[2 * jj], f[2 * jj + 1]);
      pk[2 * jj]     = (_Float16)q.x;
      pk[2 * jj + 1] = (_Float16)q.y;
    }
    ws1[t] = pk;
  } else {
    const int g  = t - NG1_;
    const int p  = g & 3;
    const int wp = (g >> 2) % WP_;
    int rest = g / (4 * WP_);
    const int h  = rest % H_;
    rest /= H_;
    const int cg = rest & 7;
    const int b  = rest >> 3;
    const int w2 = wp - MAXD_;
    const bool v = (unsigned)w2 < (unsigned)W_;
#pragma unroll
    for (int j = 0; j < 8; ++j) f[j] = 0.f;
    if (v) {
      const float* sp = in2 + ((size_t)(b * C_ + cg * 32 + p * 8) * H_ + h) * W_ + w2;
#pragma unroll
      for (int j = 0; j < 8; ++j) f[j] = sp[(size_t)j * HW_];
    }
    f16x8 pk;
#pragma unroll
    for (int jj = 0; jj < 4; ++jj) {
      half2_t q = __builtin_amdgcn_cvt_pkrtz(f[2 * jj], f[2 * jj + 1]);
      pk[2 * jj]     = (_Float16)q.x;
      pk[2 * jj + 1] = (_Float16)q.y;
    }
    ws2[g] = pk;
  }
}

// ---------------- zero-fill outputs whose h2 = h+2dy-20 is out of range ----------------
__global__ __launch_bounds__(128) void zfill_kernel(float* __restrict__ out) {
  const int t = threadIdx.x;          // w
  int blk = blockIdx.x;               // b*210 + dy*10 + slot
  const int slot = blk % 10; blk /= 10;
  const int dy = blk % 21; const int b = blk / 21;
  const int cnt = (dy < 10) ? (20 - 2 * dy) : ((dy > 10) ? (2 * dy - 20) : 0);
  const int hbase = (dy < 10) ? 0 : (116 - 2 * dy);
#pragma unroll
  for (int k = slot * 2; k < slot * 2 + 2; ++k) {
    if (k >= cnt) break;
    const int h = hbase + k;
    for (int dx = 0; dx < PATCH_; ++dx)
      out[(((size_t)b * 441 + dy * 21 + dx) * H_ + h) * W_ + t] = 0.f;
  }
}

// ---------------- main: B shared in LDS (triple-buffered), counted-vmcnt pipeline ----------------
__global__ __launch_bounds__(512, 2) void corr_mfma2(
    const f16x8* __restrict__ ws1,
    const f16x8* __restrict__ ws2,
    float* __restrict__ out) {
  // union: staging 3×448 f16x8 = 21504 B  |  transpose 8×1365 floats = 43680 B
  __shared__ __align__(16) float lds_f[8 * 1365];
  f16x8* ldsB = (f16x8*)lds_f;

  const int wid  = threadIdx.x >> 6;
  const int lane = threadIdx.x & 63;
  const int n  = lane & 15;
  const int kg = lane >> 4;
  const int src_perm = n * 4 + kg;    // pre-swizzle: LDS slot i holds granule perm(i)

  int blk = blockIdx.x;
  blk = (blk & 7) * (NBLK2_ / 8) + (blk >> 3);   // XCD-chunked; 576 blocks = one b
  const int ht = blk % 6;
  const int h2 = (blk / 6) % H_;
  const int b  = blk / (6 * H_);
  const int thalf = ht & 1;
  const int dyo   = ht >> 1;
  const int dy = dyo * 8 + wid;
  const int h  = h2 + 20 - 2 * dy;
  const bool valid = (dy <= MAXD_) && ((unsigned)h < (unsigned)H_);
  const int t0 = thalf * 4;

  const f16x8* ws2base = ws2 + ((((size_t)(b * 8) * H_ + h2) * WP_ + t0 * 16) * 4);
  const size_t sBseg = (size_t)H_ * WP_ * 4;    // per cg
  const f16x8* pA = valid
      ? (ws1 + ((((size_t)(b * 8) * H_ + h) * W_ + t0 * 16) * 4 + src_perm))
      : ws1;
  const size_t sA = (size_t)H_ * W_ * 4;

  f32x4 acc[4][4];
#pragma unroll
  for (int tt = 0; tt < 4; ++tt)
#pragma unroll
    for (int d = 0; d < 4; ++d) acc[tt][d] = f32x4{0.f, 0.f, 0.f, 0.f};

  // prologue: stage B(0) -> buf0; issue A(0) -> Areg[0]
  if (wid < 7) gload_lds16(ws2base + wid * 64 + src_perm, ldsB + wid * 64);
  f16x8 Areg[2][4];
#pragma unroll
  for (int tt = 0; tt < 4; ++tt) Areg[0][tt] = pA[tt * 64];

#pragma unroll
  for (int cg = 0; cg < 8; ++cg) {
    // ---- issue next chunk BEFORE the wait/barrier (stays in flight across it) ----
    // Triple-buffer safety: buf[(cg+1)%3] was last read in iter cg-2; every wave
    // finished those reads before crossing barrier(cg-1), which this wave has crossed.
    if (cg < 7) {
      if (wid < 7)
        gload_lds16(ws2base + (size_t)(cg + 1) * sBseg + wid * 64 + src_perm,
                    ldsB + ((cg + 1) % 3) * 448 + wid * 64);
#pragma unroll
      for (int tt = 0; tt < 4; ++tt)
        Areg[(cg + 1) & 1][tt] = pA[(size_t)(cg + 1) * sA + tt * 64];
    }
    __builtin_amdgcn_sched_barrier(0);
    // staging waves: ensure own stage(cg) retired (oldest); leave 9 younger in flight
    if (wid < 7) {
      if (cg < 7) asm volatile("s_waitcnt vmcnt(9)" ::: "memory");
      else        asm volatile("s_waitcnt vmcnt(4)" ::: "memory");
    }
    __builtin_amdgcn_sched_barrier(0);
    __builtin_amdgcn_s_barrier();     // raw barrier: no vmcnt(0) drain
    __builtin_amdgcn_sched_barrier(0);
    if (valid) {
      f16x8 Bf[7];
      const int bufo = (cg % 3) * 448;
#pragma unroll
      for (int u = 0; u < 7; ++u) Bf[u] = ldsB[bufo + u * 64 + lane];
#pragma unroll
      for (int tt = 0; tt < 4; ++tt)
#pragma unroll
        for (int d = 0; d < 4; ++d)
          acc[tt][d] = __builtin_amdgcn_mfma_f32_16x16x32_f16(
              Areg[cg & 1][tt], Bf[tt + d], acc[tt][d], 0, 0, 0);
    }
  }

  __syncthreads();   // all compute(7) reads done; reuse LDS for transpose
  float* slds = lds_f + wid * (PATCH_ * 65);
  if (valid) {
#pragma unroll
    for (int tt = 0; tt < 4; ++tt) {
#pragma unroll
      for (int r = 0; r < 4; ++r) {
        const int m = kg * 4 + r;
#pragma unroll
        for (int d = 0; d < 4; ++d) {
          const int v2 = 16 * d + n - m;     // = 2*dx
          if (!(v2 & 1) && v2 >= 0 && v2 <= 40)
            slds[(v2 >> 1) * 65 + tt * 16 + m] = acc[tt][d][r];
        }
      }
    }
    const float sc = 1.0f / (float)C_;
#pragma unroll
    for (int dx = 0; dx < PATCH_; ++dx) {
      float v = slds[dx * 65 + lane] * sc;
      v = (v >= 0.f) ? v : 0.1f * v;
      out[(((size_t)b * 441 + dy * 21 + dx) * H_ + h) * W_ + thalf * 64 + lane] = v;
    }
  }
}

// ---------------- fallback (round-6 verified): f32 inputs, dot2 path ----------------
__device__ __forceinline__ float fdot2f(half2_t a, half2_t b, float c) {
  return __builtin_amdgcn_fdot2(a, b, c, false);
}
__device__ __forceinline__ int swz(int pos) { return pos ^ ((pos >> 3) & 7); }
#define P2_ 168
#define NBLK_ (B_*24*11)

__global__ __launch_bounds__(256, 2) void corr_kernel(
    const float* __restrict__ in1,
    const float* __restrict__ in2,
    float* __restrict__ out) {
  __shared__ h8_t lds[4 * 2 * P2_];
  const int tid  = threadIdx.x;
  const int wid  = tid >> 6;
  const int lane = tid & 63;
  const int l    = lane & 15;
  const int q    = (lane >> 4) & 1;
  const int gdy  = lane >> 5;
  int bid = blockIdx.x;
  bid = (bid & 7) * (NBLK_ / 8) + (bid >> 3);
  const int dyb = bid % 11;
  const int hg  = (bid / 11) % 24;
  const int b   = bid / (11 * 24);
  const int h   = hg * 4 + wid;
  const int dy   = 2 * dyb + gdy;
  const int w0   = 8 * l;
  const int rel0 = 20 * q;
  float acc[8][11];
#pragma unroll
  for (int j = 0; j < 8; ++j)
#pragma unroll
    for (int i = 0; i < 11; ++i) acc[j][i] = 0.f;
  const int wbase   = wid * (2 * P2_);
  const int ldsbase = wbase + gdy * P2_;
  for (int c0 = 0; c0 < C_; c0 += 8) {
#pragma unroll
    for (int s = lane; s < 2 * P2_; s += 64) {
      const int dyidx = (s >= P2_) ? 1 : 0;
      const int pos = s - P2_ * dyidx;
      const int h2 = h + 2 * (2 * dyb + dyidx) - MAXD_;
      const int w2 = pos - MAXD_;
      const bool v = ((unsigned)h2 < (unsigned)H_) && ((unsigned)w2 < (unsigned)W_);
      float f[8];
      if (v) {
        const float* bp = in2 + ((size_t)(b * C_ + c0) * H_ + h2) * W_ + w2;
#pragma unroll
        for (int j = 0; j < 8; ++j) f[j] = bp[(size_t)j * HW_];
      } else {
#pragma unroll
        for (int j = 0; j < 8; ++j) f[j] = 0.f;
      }
      h8_t pk;
#pragma unroll
      for (int jj = 0; jj < 4; ++jj) {
        half2_t p2 = __builtin_amdgcn_cvt_pkrtz(f[2 * jj], f[2 * jj + 1]);
        pk[2 * jj]     = p2.x;
        pk[2 * jj + 1] = p2.y;
      }
      lds[wbase + dyidx * P2_ + swz(pos)] = pk;
    }
    const float* a_base = in1 + ((size_t)(b * C_ + c0) * H_ + h) * W_ + w0;
    half2_t a2[8][4];
#pragma unroll
    for (int jj = 0; jj < 4; ++jj) {
      f4_t lo0 = *(const f4_t*)(a_base + (size_t)(2 * jj) * HW_);
      f4_t lo1 = *(const f4_t*)(a_base + (size_t)(2 * jj) * HW_ + 4);
      f4_t hi0 = *(const f4_t*)(a_base + (size_t)(2 * jj + 1) * HW_);
      f4_t hi1 = *(const f4_t*)(a_base + (size_t)(2 * jj + 1) * HW_ + 4);
#pragma unroll
      for (int j = 0; j < 4; ++j) {
        a2[j][jj]     = __builtin_amdgcn_cvt_pkrtz(lo0[j], hi0[j]);
        a2[j + 4][jj] = __builtin_amdgcn_cvt_pkrtz(lo1[j], hi1[j]);
      }
    }
    h8_t wv[8];
#pragma unroll
    for (int k = 0; k < 8; ++k)
      wv[k] = lds[ldsbase + swz(w0 + rel0 + k)];
#pragma unroll
    for (int i = 0; i < 11; ++i) {
#pragma unroll
      for (int j = 0; j < 8; ++j) {
        const h8_t wj = wv[(2 * i + j) & 7];
#pragma unroll
        for (int jj = 0; jj < 4; ++jj) {
          half2_t bb;
          bb.x = wj[2 * jj];
          bb.y = wj[2 * jj + 1];
          acc[j][i] = fdot2f(a2[j][jj], bb, acc[j][i]);
        }
      }
      if (i < 10) {
        wv[(2 * i + 8) & 7] = lds[ldsbase + swz(w0 + rel0 + 2 * i + 8)];
        wv[(2 * i + 9) & 7] = lds[ldsbase + swz(w0 + rel0 + 2 * i + 9)];
      }
    }
  }
  if (dy < PATCH_) {
    const float s = 1.f / (float)C_;
#pragma unroll
    for (int i = 0; i < 11; ++i) {
      if (q && i == 0) continue;
      const int dx = 10 * q + i;
      float* ob = out + ((size_t)(b * (PATCH_ * PATCH_) + dy * PATCH_ + dx) * H_ + h) * W_ + w0;
      f4_t v0, v1;
#pragma unroll
      for (int j = 0; j < 4; ++j) {
        float x = acc[j][i] * s;
        v0[j] = (x >= 0.f) ? x : 0.1f * x;
        float y = acc[j + 4][i] * s;
        v1[j] = (y >= 0.f) ? y : 0.1f * y;
      }
      *(f4_t*)ob = v0;
      *(f4_t*)(ob + 4) = v1;
    }
  }
}

extern "C" void kernel_launch(void* const* d_in, const int* in_sizes, int n_in,
                              void* d_out, int out_size, void* d_ws, size_t ws_size,
                              hipStream_t stream) {
  (void)in_sizes; (void)n_in; (void)out_size;
  const float* in1 = (const float*)d_in[0];
  const float* in2 = (const float*)d_in[1];
  float* out = (float*)d_out;

  if (ws_size >= WS_NEED_) {
    f16x8* ws1 = (f16x8*)d_ws;
    f16x8* ws2 = ws1 + NG1_;
    pack_kernel<<<dim3((NG1_ + NG2_) / 256), dim3(256), 0, stream>>>(in1, in2, ws1, ws2);
    zfill_kernel<<<dim3(B_ * PATCH_ * 10), dim3(128), 0, stream>>>(out);
    corr_mfma2<<<dim3(NBLK2_), dim3(512), 0, stream>>>(ws1, ws2, out);
  } else {
    corr_kernel<<<dim3(NBLK_), dim3(256), 0, stream>>>(in1, in2, out);
  }
}

// Round 15
// 176.935 us; speedup vs baseline: 1.7107x; 1.0633x over previous
//
#include <hip/hip_runtime.h>

#define B_ 8
#define C_ 256
#define H_ 96
#define W_ 128
#define HW_ (H_*W_)
#define PATCH_ 21
#define MAXD_ 20
#define WP_ 176
#define NG1_ (B_*8*H_*W_*4)      // A granules [b][cg][h][w][p]
#define NG2_ (B_*8*H_*WP_*4)     // B granules [b][cg][h][wp][p]
#define WS_NEED_ (((size_t)NG1_ + (size_t)NG2_) * 16)
#define NBLK2_ (B_*H_*6)         // 4608 blocks: (b, h2, dyo*2+thalf)

typedef __fp16 half2_t __attribute__((ext_vector_type(2)));
typedef _Float16 f16x8 __attribute__((ext_vector_type(8)));
typedef float f32x4 __attribute__((ext_vector_type(4)));
typedef float f4_t __attribute__((ext_vector_type(4)));
typedef __fp16 h8_t __attribute__((ext_vector_type(8)));

__device__ __forceinline__ void gload_lds16(const f16x8* gsrc, f16x8* ldst) {
  __builtin_amdgcn_global_load_lds(
      (const __attribute__((address_space(1))) void*)gsrc,
      (__attribute__((address_space(3))) void*)ldst, 16, 0, 0);
}

// ---------------- prepass: f32 -> packed f16 granules, plane-interleaved ----------------
__global__ __launch_bounds__(256) void pack_kernel(
    const float* __restrict__ in1, const float* __restrict__ in2,
    f16x8* __restrict__ ws1, f16x8* __restrict__ ws2) {
  const int t = blockIdx.x * 256 + threadIdx.x;
  float f[8];
  if (t < NG1_) {
    const int p  = t & 3;
    const int w  = (t >> 2) & (W_ - 1);
    const int h  = (t >> 9) % H_;
    const int cg = (t / (4 * W_ * H_)) & 7;
    const int b  = t / (4 * W_ * H_ * 8);
    const float* sp = in1 + ((size_t)(b * C_ + cg * 32 + p * 8) * H_ + h) * W_ + w;
#pragma unroll
    for (int j = 0; j < 8; ++j) f[j] = sp[(size_t)j * HW_];
    f16x8 pk;
#pragma unroll
    for (int jj = 0; jj < 4; ++jj) {
      half2_t q = __builtin_amdgcn_cvt_pkrtz(f[2 * jj], f[2 * jj + 1]);
      pk[2 * jj]     = (_Float16)q.x;
      pk[2 * jj + 1] = (_Float16)q.y;
    }
    ws1[t] = pk;
  } else {
    const int g  = t - NG1_;
    const int p  = g & 3;
    const int wp = (g >> 2) % WP_;
    int rest = g / (4 * WP_);
    const int h  = rest % H_;
    rest /= H_;
    const int cg = rest & 7;
    const int b  = rest >> 3;
    const int w2 = wp - MAXD_;
    const bool v = (unsigned)w2 < (unsigned)W_;
#pragma unroll
    for (int j = 0; j < 8; ++j) f[j] = 0.f;
    if (v) {
      const float* sp = in2 + ((size_t)(b * C_ + cg * 32 + p * 8) * H_ + h) * W_ + w2;
#pragma unroll
      for (int j = 0; j < 8; ++j) f[j] = sp[(size_t)j * HW_];
    }
    f16x8 pk;
#pragma unroll
    for (int jj = 0; jj < 4; ++jj) {
      half2_t q = __builtin_amdgcn_cvt_pkrtz(f[2 * jj], f[2 * jj + 1]);
      pk[2 * jj]     = (_Float16)q.x;
      pk[2 * jj + 1] = (_Float16)q.y;
    }
    ws2[g] = pk;
  }
}

// ---------------- zero-fill outputs whose h2 = h+2dy-20 is out of range ----------------
__global__ __launch_bounds__(128) void zfill_kernel(float* __restrict__ out) {
  const int t = threadIdx.x;          // w
  int blk = blockIdx.x;               // b*210 + dy*10 + slot
  const int slot = blk % 10; blk /= 10;
  const int dy = blk % 21; const int b = blk / 21;
  const int cnt = (dy < 10) ? (20 - 2 * dy) : ((dy > 10) ? (2 * dy - 20) : 0);
  const int hbase = (dy < 10) ? 0 : (116 - 2 * dy);
#pragma unroll
  for (int k = slot * 2; k < slot * 2 + 2; ++k) {
    if (k >= cnt) break;
    const int h = hbase + k;
    for (int dx = 0; dx < PATCH_; ++dx)
      out[(((size_t)b * 441 + dy * 21 + dx) * H_ + h) * W_ + t] = 0.f;
  }
}

// ---------------- main: ALL of B staged once, single barrier, free-running waves ----------------
__global__ __launch_bounds__(512, 2) void corr_mfma3(
    const f16x8* __restrict__ ws1,
    const f16x8* __restrict__ ws2,
    float* __restrict__ out) {
  // union: full-B staging 8×448 granules = 57344 B  |  transpose 8×1365 floats = 43680 B
  __shared__ __align__(16) float lds_f[14336];
  f16x8* ldsB = (f16x8*)lds_f;

  const int wid  = threadIdx.x >> 6;
  const int lane = threadIdx.x & 63;
  const int n  = lane & 15;
  const int kg = lane >> 4;
  const int src_perm = n * 4 + kg;    // pre-swizzle: LDS slot i holds granule perm(i)

  int blk = blockIdx.x;
  blk = (blk & 7) * (NBLK2_ / 8) + (blk >> 3);   // XCD-chunked; 576 blocks = one b
  const int ht = blk % 6;
  const int h2 = (blk / 6) % H_;
  const int b  = blk / (6 * H_);
  const int thalf = ht & 1;
  const int dyo   = ht >> 1;
  const int dy = dyo * 8 + wid;
  const int h  = h2 + 20 - 2 * dy;
  const bool valid = (dy <= MAXD_) && ((unsigned)h < (unsigned)H_);   // wave-uniform
  const int t0 = thalf * 4;

  const f16x8* ws2base = ws2 + ((((size_t)(b * 8) * H_ + h2) * WP_ + t0 * 16) * 4);
  const size_t sBseg = (size_t)H_ * WP_ * 4;    // per cg
  const f16x8* pA = valid
      ? (ws1 + ((((size_t)(b * 8) * H_ + h) * W_ + t0 * 16) * 4 + src_perm))
      : ws1;
  const size_t sA = (size_t)H_ * W_ * 4;

  // ---- stage: wave wid stages chunk wid entirely (7 tiles, 1 KB each) ----
#pragma unroll
  for (int k = 0; k < 7; ++k)
    gload_lds16(ws2base + (size_t)wid * sBseg + k * 64 + src_perm,
                ldsB + wid * 448 + k * 64);

  f32x4 acc[4][4];
#pragma unroll
  for (int tt = 0; tt < 4; ++tt)
#pragma unroll
    for (int d = 0; d < 4; ++d) acc[tt][d] = f32x4{0.f, 0.f, 0.f, 0.f};

  f16x8 Areg[2][4];
  if (valid) {
#pragma unroll
    for (int tt = 0; tt < 4; ++tt) Areg[0][tt] = pA[tt * 64];
  }

  // the ONLY hot-path barrier: own staging retired, then block-wide sync
  asm volatile("s_waitcnt vmcnt(0)" ::: "memory");
  __builtin_amdgcn_s_barrier();
  __builtin_amdgcn_sched_barrier(0);

  if (valid) {
#pragma unroll
    for (int cg = 0; cg < 8; ++cg) {
      if (cg < 7) {
#pragma unroll
        for (int tt = 0; tt < 4; ++tt)
          Areg[(cg + 1) & 1][tt] = pA[(size_t)(cg + 1) * sA + tt * 64];
        __builtin_amdgcn_sched_barrier(0);   // pin prefetch issue above compute
      }
      // B per-u: only one B granule live at a time (VGPR budget)
#pragma unroll
      for (int u = 0; u < 7; ++u) {
        const f16x8 Bu = ldsB[cg * 448 + u * 64 + lane];
#pragma unroll
        for (int tt = 0; tt < 4; ++tt) {
          const int d = u - tt;
          if (d >= 0 && d <= 3)
            acc[tt][d] = __builtin_amdgcn_mfma_f32_16x16x32_f16(
                Areg[cg & 1][tt], Bu, acc[tt][d], 0, 0, 0);
        }
      }
    }
  }

  __syncthreads();   // staging dead; reuse LDS for transpose
  float* slds = lds_f + wid * (PATCH_ * 65);
  if (valid) {
#pragma unroll
    for (int tt = 0; tt < 4; ++tt) {
#pragma unroll
      for (int r = 0; r < 4; ++r) {
        const int m = kg * 4 + r;
#pragma unroll
        for (int d = 0; d < 4; ++d) {
          const int v2 = 16 * d + n - m;     // = 2*dx
          if (!(v2 & 1) && v2 >= 0 && v2 <= 40)
            slds[(v2 >> 1) * 65 + tt * 16 + m] = acc[tt][d][r];
        }
      }
    }
    const float sc = 1.0f / (float)C_;
#pragma unroll
    for (int dx = 0; dx < PATCH_; ++dx) {
      float v = slds[dx * 65 + lane] * sc;
      v = (v >= 0.f) ? v : 0.1f * v;
      out[(((size_t)b * 441 + dy * 21 + dx) * H_ + h) * W_ + thalf * 64 + lane] = v;
    }
  }
}

// ---------------- fallback (round-6 verified): f32 inputs, dot2 path ----------------
__device__ __forceinline__ float fdot2f(half2_t a, half2_t b, float c) {
  return __builtin_amdgcn_fdot2(a, b, c, false);
}
__device__ __forceinline__ int swz(int pos) { return pos ^ ((pos >> 3) & 7); }
#define P2_ 168
#define NBLK_ (B_*24*11)

__global__ __launch_bounds__(256, 2) void corr_kernel(
    const float* __restrict__ in1,
    const float* __restrict__ in2,
    float* __restrict__ out) {
  __shared__ h8_t lds[4 * 2 * P2_];
  const int tid  = threadIdx.x;
  const int wid  = tid >> 6;
  const int lane = tid & 63;
  const int l    = lane & 15;
  const int q    = (lane >> 4) & 1;
  const int gdy  = lane >> 5;
  int bid = blockIdx.x;
  bid = (bid & 7) * (NBLK_ / 8) + (bid >> 3);
  const int dyb = bid % 11;
  const int hg  = (bid / 11) % 24;
  const int b   = bid / (11 * 24);
  const int h   = hg * 4 + wid;
  const int dy   = 2 * dyb + gdy;
  const int w0   = 8 * l;
  const int rel0 = 20 * q;
  float acc[8][11];
#pragma unroll
  for (int j = 0; j < 8; ++j)
#pragma unroll
    for (int i = 0; i < 11; ++i) acc[j][i] = 0.f;
  const int wbase   = wid * (2 * P2_);
  const int ldsbase = wbase + gdy * P2_;
  for (int c0 = 0; c0 < C_; c0 += 8) {
#pragma unroll
    for (int s = lane; s < 2 * P2_; s += 64) {
      const int dyidx = (s >= P2_) ? 1 : 0;
      const int pos = s - P2_ * dyidx;
      const int h2 = h + 2 * (2 * dyb + dyidx) - MAXD_;
      const int w2 = pos - MAXD_;
      const bool v = ((unsigned)h2 < (unsigned)H_) && ((unsigned)w2 < (unsigned)W_);
      float f[8];
      if (v) {
        const float* bp = in2 + ((size_t)(b * C_ + c0) * H_ + h2) * W_ + w2;
#pragma unroll
        for (int j = 0; j < 8; ++j) f[j] = bp[(size_t)j * HW_];
      } else {
#pragma unroll
        for (int j = 0; j < 8; ++j) f[j] = 0.f;
      }
      h8_t pk;
#pragma unroll
      for (int jj = 0; jj < 4; ++jj) {
        half2_t p2 = __builtin_amdgcn_cvt_pkrtz(f[2 * jj], f[2 * jj + 1]);
        pk[2 * jj]     = p2.x;
        pk[2 * jj + 1] = p2.y;
      }
      lds[wbase + dyidx * P2_ + swz(pos)] = pk;
    }
    const float* a_base = in1 + ((size_t)(b * C_ + c0) * H_ + h) * W_ + w0;
    half2_t a2[8][4];
#pragma unroll
    for (int jj = 0; jj < 4; ++jj) {
      f4_t lo0 = *(const f4_t*)(a_base + (size_t)(2 * jj) * HW_);
      f4_t lo1 = *(const f4_t*)(a_base + (size_t)(2 * jj) * HW_ + 4);
      f4_t hi0 = *(const f4_t*)(a_base + (size_t)(2 * jj + 1) * HW_);
      f4_t hi1 = *(const f4_t*)(a_base + (size_t)(2 * jj + 1) * HW_ + 4);
#pragma unroll
      for (int j = 0; j < 4; ++j) {
        a2[j][jj]     = __builtin_amdgcn_cvt_pkrtz(lo0[j], hi0[j]);
        a2[j + 4][jj] = __builtin_amdgcn_cvt_pkrtz(lo1[j], hi1[j]);
      }
    }
    h8_t wv[8];
#pragma unroll
    for (int k = 0; k < 8; ++k)
      wv[k] = lds[ldsbase + swz(w0 + rel0 + k)];
#pragma unroll
    for (int i = 0; i < 11; ++i) {
#pragma unroll
      for (int j = 0; j < 8; ++j) {
        const h8_t wj = wv[(2 * i + j) & 7];
#pragma unroll
        for (int jj = 0; jj < 4; ++jj) {
          half2_t bb;
          bb.x = wj[2 * jj];
          bb.y = wj[2 * jj + 1];
          acc[j][i] = fdot2f(a2[j][jj], bb, acc[j][i]);
        }
      }
      if (i < 10) {
        wv[(2 * i + 8) & 7] = lds[ldsbase + swz(w0 + rel0 + 2 * i + 8)];
        wv[(2 * i + 9) & 7] = lds[ldsbase + swz(w0 + rel0 + 2 * i + 9)];
      }
    }
  }
  if (dy < PATCH_) {
    const float s = 1.f / (float)C_;
#pragma unroll
    for (int i = 0; i < 11; ++i) {
      if (q && i == 0) continue;
      const int dx = 10 * q + i;
      float* ob = out + ((size_t)(b * (PATCH_ * PATCH_) + dy * PATCH_ + dx) * H_ + h) * W_ + w0;
      f4_t v0, v1;
#pragma unroll
      for (int j = 0; j < 4; ++j) {
        float x = acc[j][i] * s;
        v0[j] = (x >= 0.f) ? x : 0.1f * x;
        float y = acc[j + 4][i] * s;
        v1[j] = (y >= 0.f) ? y : 0.1f * y;
      }
      *(f4_t*)ob = v0;
      *(f4_t*)(ob + 4) = v1;
    }
  }
}

extern "C" void kernel_launch(void* const* d_in, const int* in_sizes, int n_in,
                              void* d_out, int out_size, void* d_ws, size_t ws_size,
                              hipStream_t stream) {
  (void)in_sizes; (void)n_in; (void)out_size;
  const float* in1 = (const float*)d_in[0];
  const float* in2 = (const float*)d_in[1];
  float* out = (float*)d_out;

  if (ws_size >= WS_NEED_) {
    f16x8* ws1 = (f16x8*)d_ws;
    f16x8* ws2 = ws1 + NG1_;
    pack_kernel<<<dim3((NG1_ + NG2_) / 256), dim3(256), 0, stream>>>(in1, in2, ws1, ws2);
    zfill_kernel<<<dim3(B_ * PATCH_ * 10), dim3(128), 0, stream>>>(out);
    corr_mfma3<<<dim3(NBLK2_), dim3(512), 0, stream>>>(ws1, ws2, out);
  } else {
    corr_kernel<<<dim3(NBLK_), dim3(256), 0, stream>>>(in1, in2, out);
  }
}